// Round 6
// baseline (2344.728 us; speedup 1.0000x reference)
//
#include <hip/hip_runtime.h>
#include <cstdint>

typedef unsigned short u16;
typedef __attribute__((ext_vector_type(8))) short short8;
typedef __attribute__((ext_vector_type(4))) float f32x4;

#define AS1 __attribute__((address_space(1)))
#define AS3 __attribute__((address_space(3)))

#define BB 4
#define SS 8192
#define EE 1024
#define HH 16
#define DD 64
#define LL 64
#define CANDN 96

__device__ __forceinline__ void async16(const void* g, void* l) {
  __builtin_amdgcn_global_load_lds((const AS1 uint32_t*)g, (AS3 uint32_t*)l, 16, 0, 0);
}
__device__ __forceinline__ u16 f2b(float f) {  // RNE fp32 -> bf16
  uint32_t u = __float_as_uint(f);
  return (u16)((u + 0x7fffu + ((u >> 16) & 1u)) >> 16);
}
__device__ __forceinline__ float b2f(u16 h) { return __uint_as_float(((uint32_t)h) << 16); }

// ---------------- fp32 -> bf16 bulk convert (n divisible by 4) ----------------
__global__ __launch_bounds__(256) void cvt_bf16_k(const float* __restrict__ in, u16* __restrict__ out, int n4) {
  int i = blockIdx.x * 256 + threadIdx.x;
  if (i >= n4) return;
  float4 v = ((const float4*)in)[i];
  ushort4 o;
  o.x = f2b(v.x); o.y = f2b(v.y); o.z = f2b(v.z); o.w = f2b(v.w);
  ((ushort4*)out)[i] = o;
}

#define FENCE_RW()  asm volatile("s_waitcnt lgkmcnt(0)\n\ts_barrier" ::: "memory")
#define FENCE_V6()  asm volatile("s_waitcnt vmcnt(6)\n\ts_barrier" ::: "memory")
#define FENCE_V0()  asm volatile("s_waitcnt vmcnt(0)\n\ts_barrier" ::: "memory")

// ---------------- NT GEMM v2 (bf16 A): C[m,n] = sum_k A[m,k]*W[n,k] + bias[n] ----------------
// Tile 256x128, BK=64, 512 threads = 8 waves (4m x 2n), acc[4][4]/wave. Counted-vmcnt
// pipeline; LDS granule-XOR swizzle g^(row&7) applied on the pre-swizzled global SOURCE.
__global__ __launch_bounds__(512) void gemm256(const u16* __restrict__ A, const u16* __restrict__ W,
                                               const float* __restrict__ bias,
                                               float* __restrict__ Cf, u16* __restrict__ Cb, int K) {
  extern __shared__ __align__(16) u16 lds_[];
  u16* lA = lds_;            // [2][256*64]
  u16* lB = lds_ + 32768;    // [2][128*64]
  const int tid = threadIdx.x;
  const int wv = tid >> 6, lane = tid & 63;
  const int quad = lane >> 4, l15 = lane & 15;
  const int wm = wv >> 1, wn = wv & 1;   // 4 x 2 waves; per-wave out 64x64

  const int nwg = gridDim.x * gridDim.y;
  int g = blockIdx.y * gridDim.x + blockIdx.x;
  int bx = blockIdx.x, by = blockIdx.y;
  if ((nwg & 7) == 0) {
    const int chunk = nwg >> 3;
    const int v = (g & 7) * chunk + (g >> 3);
    bx = v % gridDim.x;
    by = v / gridDim.x;
  }
  const int mt = by * 256, nt = bx * 128;

  const int rl = tid >> 3;
  const int g8 = (((tid & 7) ^ (rl & 7))) * 8;
  const u16* sA00 = A + (size_t)(mt + rl) * K + g8;
  const u16* sA01 = A + (size_t)(mt + 64 + rl) * K + g8;
  const u16* sA10 = A + (size_t)(mt + 128 + rl) * K + g8;
  const u16* sA11 = A + (size_t)(mt + 192 + rl) * K + g8;
  const u16* sB0  = W + (size_t)(nt + rl) * K + g8;
  const u16* sB1  = W + (size_t)(nt + 64 + rl) * K + g8;
  const int dA = tid * 8;
  const int dB = tid * 8;

  auto STAGE = [&](int tile, int pb) {
    const int off = tile * 64;
    async16(sA00 + off, lA + pb * 16384 + dA);
    async16(sA01 + off, lA + pb * 16384 + dA + 4096);
    async16(sA10 + off, lA + pb * 16384 + 8192 + dA);
    async16(sA11 + off, lA + pb * 16384 + 8192 + dA + 4096);
    async16(sB0 + off, lB + pb * 8192 + dB);
    async16(sB1 + off, lB + pb * 8192 + dB + 4096);
  };

  f32x4 acc[4][4];
#pragma unroll
  for (int i = 0; i < 4; i++)
#pragma unroll
    for (int j = 0; j < 4; j++) acc[i][j] = (f32x4){0.f, 0.f, 0.f, 0.f};

  const int NT = K >> 6;
  STAGE(0, 0);
  STAGE(1, 1);
  FENCE_V6();  // tile0's 6 landed; tile1's 6 in flight

  for (int t = 0; t < NT; ++t) {
    const int pb = t & 1;
    const short8* pA = (const short8*)(lA + pb * 16384);
    const short8* pB = (const short8*)(lB + pb * 8192);
    short8 af[2][4], bf[2][4];
#pragma unroll
    for (int i = 0; i < 4; i++) {
      const int r = 64 * wm + 16 * i + l15;
      af[0][i] = pA[r * 8 + (quad ^ (r & 7))];
      af[1][i] = pA[r * 8 + ((quad + 4) ^ (r & 7))];
      const int rb = 64 * wn + 16 * i + l15;
      bf[0][i] = pB[rb * 8 + (quad ^ (rb & 7))];
      bf[1][i] = pB[rb * 8 + ((quad + 4) ^ (rb & 7))];
    }
#pragma unroll
    for (int i = 0; i < 4; i++)
#pragma unroll
      for (int j = 0; j < 4; j++)
        acc[i][j] = __builtin_amdgcn_mfma_f32_16x16x32_bf16(af[0][i], bf[0][j], acc[i][j], 0, 0, 0);
    FENCE_RW();                       // all reads of buf[pb] retired before DMA may land
    if (t + 2 < NT) STAGE(t + 2, pb); // overwrite just-freed buffer
#pragma unroll
    for (int i = 0; i < 4; i++)
#pragma unroll
      for (int j = 0; j < 4; j++)
        acc[i][j] = __builtin_amdgcn_mfma_f32_16x16x32_bf16(af[1][i], bf[1][j], acc[i][j], 0, 0, 0);
    if (t + 1 < NT) {
      if (t + 1 == NT - 1) { FENCE_V0(); } else { FENCE_V6(); }
    }
  }

#pragma unroll
  for (int j = 0; j < 4; j++) {
    int gn = nt + 64 * wn + 16 * j + l15;
    float bs = bias[gn];
#pragma unroll
    for (int i = 0; i < 4; i++) {
#pragma unroll
      for (int r = 0; r < 4; r++) {
        int gm = mt + 64 * wm + 16 * i + quad * 4 + r;
        float v = acc[i][j][r] + bs;
        if (Cf) Cf[(size_t)gm * EE + gn] = v;
        if (Cb) Cb[(size_t)gm * EE + gn] = f2b(v);
      }
    }
  }
}

// ---------------- NT GEMM v4 (fp32 A, fused cvt + optional fused scores) ----------------
// Tile 128x128, BK=32, 256 threads = 4 waves (2m x 2n), acc[4][4]/wave, static 32 KB LDS
// -> 5 blocks/CU (occupancy-first redesign after R4's 1-block/CU latency stall).
// A fp32 reg-staged 4 tiles ahead (ra[2][4] ping-pong, all indices compile-time literals),
// v_cvt_pk_bf16_f32 -> swizzled ds_write (granule ^ ((row>>1)&3), R0-proven mapping).
// B bf16 via pre-swizzled-source global_load_lds. Ledger: 6 vmem/tile (4 A-reg + 2 B-DMA)
// issued 2(B)/4(A) tiles ahead; end-of-tile vmcnt(6) allows only the newest 6
// (B(t+2)+A(t+4)) to remain -> B(t+1) and A(t+3) guaranteed landed.
#define LOADA(T, P) { const float4* _p = pA4 + (size_t)(T) * 8; \
  ra[P][0] = _p[0]; ra[P][1] = _p[1]; ra[P][2] = _p[2]; ra[P][3] = _p[3]; }
#define CVTA(P) { \
  asm("v_cvt_pk_bf16_f32 %0, %1, %2" : "=v"(pk0.x) : "v"(ra[P][0].x), "v"(ra[P][0].y)); \
  asm("v_cvt_pk_bf16_f32 %0, %1, %2" : "=v"(pk0.y) : "v"(ra[P][0].z), "v"(ra[P][0].w)); \
  asm("v_cvt_pk_bf16_f32 %0, %1, %2" : "=v"(pk0.z) : "v"(ra[P][1].x), "v"(ra[P][1].y)); \
  asm("v_cvt_pk_bf16_f32 %0, %1, %2" : "=v"(pk0.w) : "v"(ra[P][1].z), "v"(ra[P][1].w)); \
  asm("v_cvt_pk_bf16_f32 %0, %1, %2" : "=v"(pk1.x) : "v"(ra[P][2].x), "v"(ra[P][2].y)); \
  asm("v_cvt_pk_bf16_f32 %0, %1, %2" : "=v"(pk1.y) : "v"(ra[P][2].z), "v"(ra[P][2].w)); \
  asm("v_cvt_pk_bf16_f32 %0, %1, %2" : "=v"(pk1.z) : "v"(ra[P][3].x), "v"(ra[P][3].y)); \
  asm("v_cvt_pk_bf16_f32 %0, %1, %2" : "=v"(pk1.w) : "v"(ra[P][3].z), "v"(ra[P][3].w)); }
#define QKBODY(T, P, Q) { \
  const short8* pAl = (const short8*)lA[P]; \
  const short8* pBl = (const short8*)lB[P]; \
  short8 af[4], bfr[4]; \
  _Pragma("unroll") for (int i = 0; i < 4; i++) { \
    const int r = 64 * wm + 16 * i + l15; \
    af[i] = pAl[r * 4 + (quad ^ ((r >> 1) & 3))]; \
    const int rb = 64 * wn + 16 * i + l15; \
    bfr[i] = pBl[rb * 4 + (quad ^ ((rb >> 1) & 3))]; \
  } \
  _Pragma("unroll") for (int i = 0; i < 4; i++) \
    _Pragma("unroll") for (int j = 0; j < 4; j++) \
      acc[i][j] = __builtin_amdgcn_mfma_f32_16x16x32_bf16(af[i], bfr[j], acc[i][j], 0, 0, 0); \
  FENCE_RW(); \
  if ((T) + 2 < NT) { \
    *(int4*)(wdst0 + (P) * 4096) = pk0; \
    *(int4*)(wdst1 + (P) * 4096) = pk1; \
    async16(sB0 + ((T) + 2) * 32, &lB[P][tid * 8]); \
    async16(sB1 + ((T) + 2) * 32, &lB[P][2048 + tid * 8]); \
  } \
  if ((T) + 4 < NT) LOADA((T) + 4, P) \
  if ((T) + 3 < NT) CVTA(Q) \
  if ((T) + 1 < NT) { if ((T) + 3 < NT) { FENCE_V6(); } else { FENCE_V0(); } } }

__global__ __launch_bounds__(256, 5) void gemm_qk(const float* __restrict__ A, const u16* __restrict__ W,
                                                  const float* __restrict__ bias,
                                                  u16* __restrict__ Cb, float* __restrict__ scA, int K) {
  __shared__ __align__(16) u16 lA[2][4096];  // [2][128*32] bf16
  __shared__ __align__(16) u16 lB[2][4096];
  const int tid = threadIdx.x;
  const int wv = tid >> 6, lane = tid & 63;
  const int quad = lane >> 4, l15 = lane & 15;
  const int wm = wv >> 1, wn = wv & 1;   // 2x2 waves, per-wave out 64x64

  const int nwg = gridDim.x * gridDim.y;
  int g = blockIdx.y * gridDim.x + blockIdx.x;
  int bx = blockIdx.x, by = blockIdx.y;
  if ((nwg & 7) == 0) {
    const int chunk = nwg >> 3;
    const int v = (g & 7) * chunk + (g >> 3);
    bx = v % gridDim.x;
    by = v / gridDim.x;
  }
  const int mt = by * 128, nt = bx * 128;

  // A reg-stage: thread = half-row (row = tid>>1, 16 floats at col 16*(tid&1))
  const int K4 = K >> 2;
  const int ar_row = tid >> 1, ar_h = tid & 1;
  const int asw = (ar_row >> 1) & 3;
  const float4* pA4 = (const float4*)A + (size_t)(mt + ar_row) * K4 + 4 * ar_h;
  u16* wdst0 = &lA[0][ar_row * 32 + ((2 * ar_h + 0) ^ asw) * 8];
  u16* wdst1 = &lA[0][ar_row * 32 + ((2 * ar_h + 1) ^ asw) * 8];

  // B staging: 2 gload_lds/thread; slot j*256+tid -> row=slot>>2, phys granule tid&3,
  // source logical granule (tid&3)^((row>>1)&3) (same XOR for both j since 64%8==0 rows)
  const int brow0 = tid >> 2;
  const int bg = (tid & 3) ^ ((brow0 >> 1) & 3);
  const u16* sB0 = W + (size_t)(nt + brow0) * K + bg * 8;
  const u16* sB1 = W + (size_t)(nt + 64 + brow0) * K + bg * 8;

  float4 ra[2][4];
  int4 pk0, pk1;

  f32x4 acc[4][4];
#pragma unroll
  for (int i = 0; i < 4; i++)
#pragma unroll
    for (int j = 0; j < 4; j++) acc[i][j] = (f32x4){0.f, 0.f, 0.f, 0.f};

  const int NT = K >> 5;  // BK=32; NT even (K=1024 -> 32), NT >= 4 assumed

  // prologue: lA[0/1] <- cvt(A(0/1)); lB[0/1] <- B(0/1); pk <- A(2); ra holds A(2),A(3)
  LOADA(0, 0) LOADA(1, 1)
  async16(sB0, &lB[0][tid * 8]);
  async16(sB1, &lB[0][2048 + tid * 8]);
  async16(sB0 + 32, &lB[1][tid * 8]);
  async16(sB1 + 32, &lB[1][2048 + tid * 8]);
  CVTA(0)
  *(int4*)wdst0 = pk0; *(int4*)wdst1 = pk1;
  CVTA(1)
  *(int4*)(wdst0 + 4096) = pk0; *(int4*)(wdst1 + 4096) = pk1;
  LOADA(2, 0) LOADA(3, 1)
  CVTA(0)  // pk = A(2)
  // vmcnt(8): newest 8 = A(2)+A(3) reg loads -> B(0),B(1) DMA guaranteed landed
  asm volatile("s_waitcnt lgkmcnt(0) vmcnt(8)\n\ts_barrier" ::: "memory");

  for (int tt = 0; tt < NT; tt += 2) {
    QKBODY(tt, 0, 1)
    QKBODY(tt + 1, 1, 0)
  }

  // epilogue: bias + bf16 store; optional fused row-norm scores (wave's 64 cols = 1 head)
  float bs[4];
#pragma unroll
  for (int j = 0; j < 4; j++) bs[j] = bias[nt + 64 * wn + 16 * j + l15];
#pragma unroll
  for (int i = 0; i < 4; i++) {
#pragma unroll
    for (int r = 0; r < 4; r++) {
      const int gm = mt + 64 * wm + 16 * i + quad * 4 + r;
      float nrm = 0.f;
#pragma unroll
      for (int j = 0; j < 4; j++) {
        float v = acc[i][j][r] + bs[j];
        Cb[(size_t)gm * EE + (nt + 64 * wn + 16 * j + l15)] = f2b(v);
        nrm += v * v;
      }
      if (scA) {
#pragma unroll
        for (int m = 1; m < 16; m <<= 1) nrm += __shfl_xor(nrm, m, 64);
        if (l15 == 0) atomicAdd(&scA[gm], sqrtf(nrm) * (1.f / 16.f));
      }
    }
  }
}

// ---------------- stage-1 topk: exact top-96 set per batch (order-free) ----------------
#define TKT 1024
#define EQCAP 256
__global__ __launch_bounds__(TKT) void topk1_k(const float* __restrict__ sc, int* __restrict__ cand) {
  const int b = blockIdx.x;
  __shared__ uint32_t s[SS];
  __shared__ int wsum[TKT / 64];
  __shared__ int cnt_sh;
  __shared__ int counter, eqcount;
  __shared__ int eqbuf[EQCAP];
  const int tid = threadIdx.x;
  const int lane = tid & 63, wv = tid >> 6;
  for (int i = tid; i < SS; i += TKT) s[i] = __float_as_uint(sc[b * SS + i]);
  if (tid == 0) { counter = 0; eqcount = 0; }
  __syncthreads();

  uint32_t lo = 0u, hi = 0x7f7fffffu;
  while (lo < hi) {
    uint32_t mid = lo + ((hi - lo + 1) >> 1);
    int c = 0;
    for (int i = tid; i < SS; i += TKT) c += (s[i] >= mid) ? 1 : 0;
#pragma unroll
    for (int m = 1; m < 64; m <<= 1) c += __shfl_xor(c, m, 64);
    if (lane == 0) wsum[wv] = c;
    __syncthreads();
    if (tid == 0) {
      int t = 0;
#pragma unroll
      for (int w = 0; w < TKT / 64; w++) t += wsum[w];
      cnt_sh = t;
    }
    __syncthreads();
    if (cnt_sh >= CANDN) lo = mid; else hi = mid - 1;
    __syncthreads();
  }
  const uint32_t T = lo;  // count(u>T) < CANDN <= count(u>=T)

  for (int i = tid; i < SS; i += TKT) {
    uint32_t u = s[i];
    if (u > T) {
      int p = atomicAdd(&counter, 1);
      cand[b * CANDN + p] = i;
    } else if (u == T) {
      int p = atomicAdd(&eqcount, 1);
      if (p < EQCAP) eqbuf[p] = i;
    }
  }
  __syncthreads();
  const int above = counter;
  const int rem = CANDN - above;
  int ec = eqcount; if (ec > EQCAP) ec = EQCAP;
  __syncthreads();
  for (int i = tid; i < ec; i += TKT) {
    int me = eqbuf[i];
    int rank = 0;
    for (int j = 0; j < ec; j++) rank += (eqbuf[j] < me) ? 1 : 0;
    if (rank < rem) {
      int p = atomicAdd(&counter, 1);
      cand[b * CANDN + p] = me;
    }
  }
}

// ---------------- stage-2: exact fp64 k for candidates ----------------
__global__ __launch_bounds__(256) void rescore_k(const float* __restrict__ key, const float* __restrict__ Wk,
                                                 const int* __restrict__ cand, double* __restrict__ kpart) {
  const int kc = blockIdx.x, h = blockIdx.y, b = blockIdx.z;
  const int d = threadIdx.x & 63, cg = threadIdx.x >> 6;
  __shared__ float wk[64 * 257];   // padded: 64 rows stride 257
  __shared__ float xs[24 * 256];
  for (int i = threadIdx.x; i < 64 * 256; i += 256)
    wk[(i >> 8) * 257 + (i & 255)] = Wk[(size_t)(h * 64 + (i >> 8)) * EE + kc * 256 + (i & 255)];
  for (int c0 = 0; c0 < CANDN; c0 += 24) {
    __syncthreads();
    for (int i = threadIdx.x; i < 24 * 256; i += 256) {
      int c = c0 + (i >> 8);
      xs[i] = key[((size_t)b * SS + cand[b * CANDN + c]) * EE + kc * 256 + (i & 255)];
    }
    __syncthreads();
    double acc[6] = {0, 0, 0, 0, 0, 0};
    for (int kk = 0; kk < 256; kk++) {
      double wv_ = (double)wk[d * 257 + kk];
#pragma unroll
      for (int j = 0; j < 6; j++)
        acc[j] += wv_ * (double)xs[(cg * 6 + j) * 256 + kk];
    }
#pragma unroll
    for (int j = 0; j < 6; j++) {
      int c = c0 + cg * 6 + j;
      kpart[(((size_t)kc * BB + b) * CANDN + c) * 1024 + h * 64 + d] = acc[j];
    }
  }
}

// exact fp64 candidate scores
__global__ __launch_bounds__(64) void score2_k(const double* __restrict__ kpart, const float* __restrict__ bk,
                                               double* __restrict__ sc2) {
  const int c = blockIdx.x, b = blockIdx.y;
  const int lane = threadIdx.x;
  double tot = 0.0;
  for (int h = 0; h < HH; h++) {
    double v = (double)bk[h * 64 + lane];
#pragma unroll
    for (int kc = 0; kc < 4; kc++)
      v += kpart[(((size_t)kc * BB + b) * CANDN + c) * 1024 + h * 64 + lane];
    double s = v * v;
#pragma unroll
    for (int m = 1; m < 64; m <<= 1) s += __shfl_xor(s, m, 64);
    tot += sqrt(s);
  }
  if (lane == 0) sc2[b * CANDN + c] = tot * (1.0 / 16.0);
}

// exact rank among candidates -> final idx in descending order (tie: lower index first)
__global__ __launch_bounds__(128) void topk2_k(const double* __restrict__ sc2, const int* __restrict__ cand,
                                               int* __restrict__ idxf) {
  const int b = blockIdx.x, t = threadIdx.x;
  if (t >= CANDN) return;
  double my = sc2[b * CANDN + t];
  int mi = cand[b * CANDN + t];
  int rank = 0;
  for (int j = 0; j < CANDN; j++) {
    double sj = sc2[b * CANDN + j];
    int ij = cand[b * CANDN + j];
    if (sj > my || (sj == my && ij < mi)) rank++;
  }
  if (rank < LL) idxf[b * LL + rank] = mi;
}

// gather value rows for the selected indices (fp32 -> bf16)
__global__ __launch_bounds__(256) void gatherx_k(const float* __restrict__ value, const int* __restrict__ idxf,
                                                 u16* __restrict__ xg) {
  const int r = blockIdx.x;  // b*64 + l
  const int b = r >> 6;
  const float* src = value + ((size_t)b * SS + idxf[r]) * EE;
  for (int i = threadIdx.x; i < EE; i += 256) xg[(size_t)r * EE + i] = f2b(src[i]);
}

// build k_sp[(b,h),l,d] (bf16) and v_spT[(b,h),d,l] (bf16)
__global__ __launch_bounds__(64) void gathersp_k(const u16* __restrict__ kb, const float* __restrict__ vg,
                                                 const int* __restrict__ idxf,
                                                 u16* __restrict__ ksp, u16* __restrict__ vspT) {
  const int g = blockIdx.x;  // (b*16+h)*64 + l
  const int l = g & 63, h = (g >> 6) & 15, b = g >> 10;
  const int d = threadIdx.x;
  ksp[(size_t)g * 64 + d] = kb[((size_t)b * SS + idxf[b * 64 + l]) * EE + h * 64 + d];
  vspT[((size_t)(b * 16 + h) * 64 + d) * 64 + l] = f2b(vg[((size_t)b * 64 + l) * EE + h * 64 + d]);
}

// ---------------- fused attention: QK^T -> softmax -> w out -> PV -> attn out ----------------
__global__ __launch_bounds__(256) void attn_k(const u16* __restrict__ qb, const u16* __restrict__ ksp,
                                              const u16* __restrict__ vspT,
                                              float* __restrict__ wout, u16* __restrict__ attnb) {
  __shared__ __align__(16) u16 qt[4096];
  __shared__ __align__(16) u16 kt[4096];
  __shared__ __align__(16) u16 vt[4096];
  __shared__ __align__(16) u16 wt[4096];
  const int tid = threadIdx.x;
  const int wv = tid >> 6, lane = tid & 63, quad = lane >> 4, l15 = lane & 15;
  const int s0 = blockIdx.x * 64;
  const int bh = blockIdx.y, b = bh >> 4, h = bh & 15;

  {
    const int bi0 = tid, bi1 = 256 + tid;
    const int r0 = bi0 >> 3, c0 = (bi0 & 7) ^ (r0 & 7);
    const int r1 = bi1 >> 3, c1 = (bi1 & 7) ^ (r1 & 7);
    const u16* qg = qb + ((size_t)b * SS + s0) * EE + h * 64;
    async16(qg + (size_t)r0 * EE + c0 * 8, qt + bi0 * 8);
    async16(qg + (size_t)r1 * EE + c1 * 8, qt + bi1 * 8);
    const u16* kg = ksp + (size_t)bh * 4096;
    async16(kg + r0 * 64 + c0 * 8, kt + bi0 * 8);
    async16(kg + r1 * 64 + c1 * 8, kt + bi1 * 8);
    const u16* vgp = vspT + (size_t)bh * 4096;
    async16(vgp + r0 * 64 + c0 * 8, vt + bi0 * 8);
    async16(vgp + r1 * 64 + c1 * 8, vt + bi1 * 8);
  }
  __syncthreads();

  f32x4 acc[4];
#pragma unroll
  for (int j = 0; j < 4; j++) acc[j] = (f32x4){0.f, 0.f, 0.f, 0.f};
  const int ar = 16 * wv + l15;
#pragma unroll
  for (int ks = 0; ks < 2; ks++) {
    const int cg = quad + ks * 4;
    short8 af = ((const short8*)qt)[ar * 8 + (cg ^ (ar & 7))];
#pragma unroll
    for (int j = 0; j < 4; j++) {
      int br = 16 * j + l15;
      short8 bf = ((const short8*)kt)[br * 8 + (cg ^ (br & 7))];
      acc[j] = __builtin_amdgcn_mfma_f32_16x16x32_bf16(af, bf, acc[j], 0, 0, 0);
    }
  }
#pragma unroll
  for (int j = 0; j < 4; j++) acc[j] *= 0.125f;  // 1/sqrt(D)

  float inv[4];
#pragma unroll
  for (int r = 0; r < 4; r++) {
    float m = fmaxf(fmaxf(acc[0][r], acc[1][r]), fmaxf(acc[2][r], acc[3][r]));
#pragma unroll
    for (int msk = 1; msk < 16; msk <<= 1) m = fmaxf(m, __shfl_xor(m, msk, 64));
    float e0 = __expf(acc[0][r] - m);
    float e1 = __expf(acc[1][r] - m);
    float e2 = __expf(acc[2][r] - m);
    float e3 = __expf(acc[3][r] - m);
    acc[0][r] = e0; acc[1][r] = e1; acc[2][r] = e2; acc[3][r] = e3;
    float s = e0 + e1 + e2 + e3;
#pragma unroll
    for (int msk = 1; msk < 16; msk <<= 1) s += __shfl_xor(s, msk, 64);
    inv[r] = 1.f / s;
  }

  const size_t wbase = ((size_t)bh * SS + s0 + 16 * wv) * 64;
#pragma unroll
  for (int j = 0; j < 4; j++) {
#pragma unroll
    for (int r = 0; r < 4; r++) {
      float val = acc[j][r] * inv[r];
      int rowl = quad * 4 + r;
      int l = 16 * j + l15;
      wout[wbase + (size_t)rowl * 64 + l] = val;
      int wr = 16 * wv + rowl;
      wt[wr * 64 + ((l >> 3) ^ (wr & 7)) * 8 + (l & 7)] = f2b(val);
    }
  }
  __syncthreads();

  f32x4 acc2[4];
#pragma unroll
  for (int j = 0; j < 4; j++) acc2[j] = (f32x4){0.f, 0.f, 0.f, 0.f};
#pragma unroll
  for (int ks = 0; ks < 2; ks++) {
    const int cg = quad + ks * 4;
    short8 af = ((const short8*)wt)[ar * 8 + (cg ^ (ar & 7))];
#pragma unroll
    for (int j = 0; j < 4; j++) {
      int br = 16 * j + l15;
      short8 bf = ((const short8*)vt)[br * 8 + (cg ^ (br & 7))];
      acc2[j] = __builtin_amdgcn_mfma_f32_16x16x32_bf16(af, bf, acc2[j], 0, 0, 0);
    }
  }
#pragma unroll
  for (int j = 0; j < 4; j++)
#pragma unroll
    for (int r = 0; r < 4; r++)
      attnb[((size_t)b * SS + s0 + 16 * wv + quad * 4 + r) * EE + h * 64 + 16 * j + l15] = f2b(acc2[j][r]);
}

extern "C" void kernel_launch(void* const* d_in, const int* in_sizes, int n_in,
                              void* d_out, int out_size, void* d_ws, size_t ws_size,
                              hipStream_t stream) {
  (void)in_sizes; (void)n_in; (void)out_size; (void)ws_size;
  const float* query = (const float*)d_in[0];
  const float* key   = (const float*)d_in[1];
  const float* value = (const float*)d_in[2];
  const float* Wq = (const float*)d_in[3];
  const float* bq = (const float*)d_in[4];
  const float* Wk = (const float*)d_in[5];
  const float* bk = (const float*)d_in[6];
  const float* Wv = (const float*)d_in[7];
  const float* bv = (const float*)d_in[8];
  const float* Wo = (const float*)d_in[9];
  const float* bo = (const float*)d_in[10];
  float* out = (float*)d_out;
  float* wout = out + (size_t)BB * SS * EE;

  char* p = (char*)d_ws;
  auto alloc = [&](size_t n) { char* r = p; p += (n + 255) & ~(size_t)255; return r; };
  u16* qbf = (u16*)alloc((size_t)BB * SS * EE * 2);   // reused as attn output buffer
  u16* kbf = (u16*)alloc((size_t)BB * SS * EE * 2);   // (unused; kept for layout stability)
  u16* wqb = (u16*)alloc((size_t)EE * EE * 2);
  u16* wkb = (u16*)alloc((size_t)EE * EE * 2);
  u16* wvb = (u16*)alloc((size_t)EE * EE * 2);
  u16* wob = (u16*)alloc((size_t)EE * EE * 2);
  u16* qb  = (u16*)alloc((size_t)BB * SS * EE * 2);
  u16* kb  = (u16*)alloc((size_t)BB * SS * EE * 2);
  float*  sc    = (float*)alloc((size_t)BB * SS * 4);
  int*    cand  = (int*)alloc(BB * CANDN * 4);
  double* kpart = (double*)alloc((size_t)4 * BB * CANDN * 1024 * 8);
  double* sc2   = (double*)alloc(BB * CANDN * 8);
  int*    idxf  = (int*)alloc(BB * LL * 4);
  u16*    xg    = (u16*)alloc((size_t)BB * LL * EE * 2);
  float*  vg    = (float*)alloc((size_t)BB * LL * EE * 4);
  u16*    ksp   = (u16*)alloc((size_t)BB * HH * LL * DD * 2);
  u16*    vspT  = (u16*)alloc((size_t)BB * HH * DD * LL * 2);
  u16*    attnb = qbf;  // reuse

  const int M = BB * SS;
  const size_t gemm_lds = 98304;  // gemm256: 2*(256*64 + 128*64) u16

  cvt_bf16_k<<<(EE * EE / 4 + 255) / 256, 256, 0, stream>>>(Wq, wqb, EE * EE / 4);
  cvt_bf16_k<<<(EE * EE / 4 + 255) / 256, 256, 0, stream>>>(Wk, wkb, EE * EE / 4);
  cvt_bf16_k<<<(EE * EE / 4 + 255) / 256, 256, 0, stream>>>(Wv, wvb, EE * EE / 4);
  cvt_bf16_k<<<(EE * EE / 4 + 255) / 256, 256, 0, stream>>>(Wo, wob, EE * EE / 4);
  hipMemsetAsync(sc, 0, (size_t)M * 4, stream);

  dim3 gq(EE / 128, M / 128);
  gemm_qk<<<gq, 256, 0, stream>>>(query, wqb, bq, qb, nullptr, EE);  // Q proj (fused cvt)
  gemm_qk<<<gq, 256, 0, stream>>>(key, wkb, bk, kb, sc, EE);         // K proj + fused scores

  topk1_k<<<BB, TKT, 0, stream>>>(sc, cand);
  rescore_k<<<dim3(4, HH, BB), 256, 0, stream>>>(key, Wk, cand, kpart);
  score2_k<<<dim3(CANDN, BB), 64, 0, stream>>>(kpart, bk, sc2);
  topk2_k<<<BB, 128, 0, stream>>>(sc2, cand, idxf);

  gatherx_k<<<BB * LL, 256, 0, stream>>>(value, idxf, xg);
  gemm256<<<dim3(EE / 128, BB * LL / 256), 512, gemm_lds, stream>>>(xg, wvb, bv, vg, nullptr, EE);  // V on 256 rows
  gathersp_k<<<BB * HH * LL, 64, 0, stream>>>(kb, vg, idxf, ksp, vspT);

  attn_k<<<dim3(SS / 64, BB * HH), 256, 0, stream>>>(qb, ksp, vspT, wout, attnb);

  gemm256<<<dim3(EE / 128, M / 256), 512, gemm_lds, stream>>>(attnb, wob, bo, out, nullptr, EE); // output projection
}

// Round 7
// 1022.782 us; speedup vs baseline: 2.2925x; 2.2925x over previous
//
#include <hip/hip_runtime.h>
#include <cstdint>

typedef unsigned short u16;
typedef __attribute__((ext_vector_type(8))) short short8;
typedef __attribute__((ext_vector_type(4))) float f32x4;

#define AS1 __attribute__((address_space(1)))
#define AS3 __attribute__((address_space(3)))

#define BB 4
#define SS 8192
#define EE 1024
#define HH 16
#define DD 64
#define LL 64
#define CANDN 96

__device__ __forceinline__ void async16(const void* g, void* l) {
  __builtin_amdgcn_global_load_lds((const AS1 uint32_t*)g, (AS3 uint32_t*)l, 16, 0, 0);
}
__device__ __forceinline__ u16 f2b(float f) {  // RNE fp32 -> bf16
  uint32_t u = __float_as_uint(f);
  return (u16)((u + 0x7fffu + ((u >> 16) & 1u)) >> 16);
}
__device__ __forceinline__ float b2f(u16 h) { return __uint_as_float(((uint32_t)h) << 16); }

// ---------------- fp32 -> bf16 bulk convert (n divisible by 4) ----------------
__global__ __launch_bounds__(256) void cvt_bf16_k(const float* __restrict__ in, u16* __restrict__ out, int n4) {
  int i = blockIdx.x * 256 + threadIdx.x;
  if (i >= n4) return;
  float4 v = ((const float4*)in)[i];
  ushort4 o;
  o.x = f2b(v.x); o.y = f2b(v.y); o.z = f2b(v.z); o.w = f2b(v.w);
  ((ushort4*)out)[i] = o;
}

#define FENCE_RW()  asm volatile("s_waitcnt lgkmcnt(0)\n\ts_barrier" ::: "memory")
#define FENCE_V6()  asm volatile("s_waitcnt vmcnt(6)\n\ts_barrier" ::: "memory")
#define FENCE_V0()  asm volatile("s_waitcnt vmcnt(0)\n\ts_barrier" ::: "memory")

// ---------------- NT GEMM v2 (bf16 A): C[m,n] = sum_k A[m,k]*W[n,k] + bias[n] ----------------
// Tile 256x128, BK=64, 512 threads = 8 waves (4m x 2n), acc[4][4]/wave. Counted-vmcnt
// pipeline; LDS granule-XOR swizzle g^(row&7) applied on the pre-swizzled global SOURCE.
__global__ __launch_bounds__(512) void gemm256(const u16* __restrict__ A, const u16* __restrict__ W,
                                               const float* __restrict__ bias,
                                               float* __restrict__ Cf, u16* __restrict__ Cb, int K) {
  extern __shared__ __align__(16) u16 lds_[];
  u16* lA = lds_;            // [2][256*64]
  u16* lB = lds_ + 32768;    // [2][128*64]
  const int tid = threadIdx.x;
  const int wv = tid >> 6, lane = tid & 63;
  const int quad = lane >> 4, l15 = lane & 15;
  const int wm = wv >> 1, wn = wv & 1;   // 4 x 2 waves; per-wave out 64x64

  const int nwg = gridDim.x * gridDim.y;
  int g = blockIdx.y * gridDim.x + blockIdx.x;
  int bx = blockIdx.x, by = blockIdx.y;
  if ((nwg & 7) == 0) {
    const int chunk = nwg >> 3;
    const int v = (g & 7) * chunk + (g >> 3);
    bx = v % gridDim.x;
    by = v / gridDim.x;
  }
  const int mt = by * 256, nt = bx * 128;

  const int rl = tid >> 3;
  const int g8 = (((tid & 7) ^ (rl & 7))) * 8;
  const u16* sA00 = A + (size_t)(mt + rl) * K + g8;
  const u16* sA01 = A + (size_t)(mt + 64 + rl) * K + g8;
  const u16* sA10 = A + (size_t)(mt + 128 + rl) * K + g8;
  const u16* sA11 = A + (size_t)(mt + 192 + rl) * K + g8;
  const u16* sB0  = W + (size_t)(nt + rl) * K + g8;
  const u16* sB1  = W + (size_t)(nt + 64 + rl) * K + g8;
  const int dA = tid * 8;
  const int dB = tid * 8;

  auto STAGE = [&](int tile, int pb) {
    const int off = tile * 64;
    async16(sA00 + off, lA + pb * 16384 + dA);
    async16(sA01 + off, lA + pb * 16384 + dA + 4096);
    async16(sA10 + off, lA + pb * 16384 + 8192 + dA);
    async16(sA11 + off, lA + pb * 16384 + 8192 + dA + 4096);
    async16(sB0 + off, lB + pb * 8192 + dB);
    async16(sB1 + off, lB + pb * 8192 + dB + 4096);
  };

  f32x4 acc[4][4];
#pragma unroll
  for (int i = 0; i < 4; i++)
#pragma unroll
    for (int j = 0; j < 4; j++) acc[i][j] = (f32x4){0.f, 0.f, 0.f, 0.f};

  const int NT = K >> 6;
  STAGE(0, 0);
  STAGE(1, 1);
  FENCE_V6();  // tile0's 6 landed; tile1's 6 in flight

  for (int t = 0; t < NT; ++t) {
    const int pb = t & 1;
    const short8* pA = (const short8*)(lA + pb * 16384);
    const short8* pB = (const short8*)(lB + pb * 8192);
    short8 af[2][4], bf[2][4];
#pragma unroll
    for (int i = 0; i < 4; i++) {
      const int r = 64 * wm + 16 * i + l15;
      af[0][i] = pA[r * 8 + (quad ^ (r & 7))];
      af[1][i] = pA[r * 8 + ((quad + 4) ^ (r & 7))];
      const int rb = 64 * wn + 16 * i + l15;
      bf[0][i] = pB[rb * 8 + (quad ^ (rb & 7))];
      bf[1][i] = pB[rb * 8 + ((quad + 4) ^ (rb & 7))];
    }
#pragma unroll
    for (int i = 0; i < 4; i++)
#pragma unroll
      for (int j = 0; j < 4; j++)
        acc[i][j] = __builtin_amdgcn_mfma_f32_16x16x32_bf16(af[0][i], bf[0][j], acc[i][j], 0, 0, 0);
    FENCE_RW();                       // all reads of buf[pb] retired before DMA may land
    if (t + 2 < NT) STAGE(t + 2, pb); // overwrite just-freed buffer
#pragma unroll
    for (int i = 0; i < 4; i++)
#pragma unroll
      for (int j = 0; j < 4; j++)
        acc[i][j] = __builtin_amdgcn_mfma_f32_16x16x32_bf16(af[1][i], bf[1][j], acc[i][j], 0, 0, 0);
    if (t + 1 < NT) {
      if (t + 1 == NT - 1) { FENCE_V0(); } else { FENCE_V6(); }
    }
  }

#pragma unroll
  for (int j = 0; j < 4; j++) {
    int gn = nt + 64 * wn + 16 * j + l15;
    float bs = bias[gn];
#pragma unroll
    for (int i = 0; i < 4; i++) {
#pragma unroll
      for (int r = 0; r < 4; r++) {
        int gm = mt + 64 * wm + 16 * i + quad * 4 + r;
        float v = acc[i][j][r] + bs;
        if (Cf) Cf[(size_t)gm * EE + gn] = v;
        if (Cb) Cb[(size_t)gm * EE + gn] = f2b(v);
      }
    }
  }
}

// ---------------- NT GEMM v4 (fp32 A, fused cvt + optional fused scores) ----------------
// Tile 128x128, BK=32, 256 threads = 4 waves (2m x 2n), acc[4][4]/wave, static 32 KB LDS.
// __launch_bounds__(256) ONLY: R6's (256,5) capped regs at ~102/wave -> acc spilled to
// scratch (VGPR=48, WRITE_SIZE 2 GB, 844 us). Natural allocation ~160-200 regs -> 2-3
// blocks/CU via VGPR, LDS allows 5 -> no spill, still multi-block occupancy.
// A fp32 reg-staged 4 tiles ahead (ra[2][4] ping-pong, literal indices),
// v_cvt_pk_bf16_f32 -> swizzled ds_write (granule ^ ((row>>1)&3), R0-proven mapping).
// B bf16 via pre-swizzled-source global_load_lds. Ledger: 6 vmem/tile (4 A-reg + 2 B-DMA)
// issued 2(B)/4(A) tiles ahead; end-of-tile vmcnt(6) allows only the newest 6
// (B(t+2)+A(t+4)) to remain -> B(t+1) and A(t+3) guaranteed landed.
#define LOADA(T, P) { const float4* _p = pA4 + (size_t)(T) * 8; \
  ra[P][0] = _p[0]; ra[P][1] = _p[1]; ra[P][2] = _p[2]; ra[P][3] = _p[3]; }
#define CVTA(P) { \
  asm("v_cvt_pk_bf16_f32 %0, %1, %2" : "=v"(pk0.x) : "v"(ra[P][0].x), "v"(ra[P][0].y)); \
  asm("v_cvt_pk_bf16_f32 %0, %1, %2" : "=v"(pk0.y) : "v"(ra[P][0].z), "v"(ra[P][0].w)); \
  asm("v_cvt_pk_bf16_f32 %0, %1, %2" : "=v"(pk0.z) : "v"(ra[P][1].x), "v"(ra[P][1].y)); \
  asm("v_cvt_pk_bf16_f32 %0, %1, %2" : "=v"(pk0.w) : "v"(ra[P][1].z), "v"(ra[P][1].w)); \
  asm("v_cvt_pk_bf16_f32 %0, %1, %2" : "=v"(pk1.x) : "v"(ra[P][2].x), "v"(ra[P][2].y)); \
  asm("v_cvt_pk_bf16_f32 %0, %1, %2" : "=v"(pk1.y) : "v"(ra[P][2].z), "v"(ra[P][2].w)); \
  asm("v_cvt_pk_bf16_f32 %0, %1, %2" : "=v"(pk1.z) : "v"(ra[P][3].x), "v"(ra[P][3].y)); \
  asm("v_cvt_pk_bf16_f32 %0, %1, %2" : "=v"(pk1.w) : "v"(ra[P][3].z), "v"(ra[P][3].w)); }
#define QKBODY(T, P, Q) { \
  const short8* pAl = (const short8*)lA[P]; \
  const short8* pBl = (const short8*)lB[P]; \
  short8 af[4], bfr[4]; \
  _Pragma("unroll") for (int i = 0; i < 4; i++) { \
    const int r = 64 * wm + 16 * i + l15; \
    af[i] = pAl[r * 4 + (quad ^ ((r >> 1) & 3))]; \
    const int rb = 64 * wn + 16 * i + l15; \
    bfr[i] = pBl[rb * 4 + (quad ^ ((rb >> 1) & 3))]; \
  } \
  _Pragma("unroll") for (int i = 0; i < 4; i++) \
    _Pragma("unroll") for (int j = 0; j < 4; j++) \
      acc[i][j] = __builtin_amdgcn_mfma_f32_16x16x32_bf16(af[i], bfr[j], acc[i][j], 0, 0, 0); \
  FENCE_RW(); \
  if ((T) + 2 < NT) { \
    *(int4*)(wdst0 + (P) * 4096) = pk0; \
    *(int4*)(wdst1 + (P) * 4096) = pk1; \
    async16(sB0 + ((T) + 2) * 32, &lB[P][tid * 8]); \
    async16(sB1 + ((T) + 2) * 32, &lB[P][2048 + tid * 8]); \
  } \
  if ((T) + 4 < NT) LOADA((T) + 4, P) \
  if ((T) + 3 < NT) CVTA(Q) \
  if ((T) + 1 < NT) { if ((T) + 3 < NT) { FENCE_V6(); } else { FENCE_V0(); } } }

__global__ __launch_bounds__(256) void gemm_qk(const float* __restrict__ A, const u16* __restrict__ W,
                                               const float* __restrict__ bias,
                                               u16* __restrict__ Cb, float* __restrict__ scA, int K) {
  __shared__ __align__(16) u16 lA[2][4096];  // [2][128*32] bf16
  __shared__ __align__(16) u16 lB[2][4096];
  const int tid = threadIdx.x;
  const int wv = tid >> 6, lane = tid & 63;
  const int quad = lane >> 4, l15 = lane & 15;
  const int wm = wv >> 1, wn = wv & 1;   // 2x2 waves, per-wave out 64x64

  const int nwg = gridDim.x * gridDim.y;
  int g = blockIdx.y * gridDim.x + blockIdx.x;
  int bx = blockIdx.x, by = blockIdx.y;
  if ((nwg & 7) == 0) {
    const int chunk = nwg >> 3;
    const int v = (g & 7) * chunk + (g >> 3);
    bx = v % gridDim.x;
    by = v / gridDim.x;
  }
  const int mt = by * 128, nt = bx * 128;

  // A reg-stage: thread = half-row (row = tid>>1, 16 floats at col 16*(tid&1))
  const int K4 = K >> 2;
  const int ar_row = tid >> 1, ar_h = tid & 1;
  const int asw = (ar_row >> 1) & 3;
  const float4* pA4 = (const float4*)A + (size_t)(mt + ar_row) * K4 + 4 * ar_h;
  u16* wdst0 = &lA[0][ar_row * 32 + ((2 * ar_h + 0) ^ asw) * 8];
  u16* wdst1 = &lA[0][ar_row * 32 + ((2 * ar_h + 1) ^ asw) * 8];

  // B staging: 2 gload_lds/thread; slot j*256+tid -> row=slot>>2, phys granule tid&3,
  // source logical granule (tid&3)^((row>>1)&3)
  const int brow0 = tid >> 2;
  const int bg = (tid & 3) ^ ((brow0 >> 1) & 3);
  const u16* sB0 = W + (size_t)(nt + brow0) * K + bg * 8;
  const u16* sB1 = W + (size_t)(nt + 64 + brow0) * K + bg * 8;

  float4 ra[2][4];
  int4 pk0, pk1;

  f32x4 acc[4][4];
#pragma unroll
  for (int i = 0; i < 4; i++)
#pragma unroll
    for (int j = 0; j < 4; j++) acc[i][j] = (f32x4){0.f, 0.f, 0.f, 0.f};

  const int NT = K >> 5;  // BK=32; NT even (K=1024 -> 32), NT >= 4 assumed

  // prologue: lA[0/1] <- cvt(A(0/1)); lB[0/1] <- B(0/1); pk <- A(2); ra holds A(2),A(3)
  LOADA(0, 0) LOADA(1, 1)
  async16(sB0, &lB[0][tid * 8]);
  async16(sB1, &lB[0][2048 + tid * 8]);
  async16(sB0 + 32, &lB[1][tid * 8]);
  async16(sB1 + 32, &lB[1][2048 + tid * 8]);
  CVTA(0)
  *(int4*)wdst0 = pk0; *(int4*)wdst1 = pk1;
  CVTA(1)
  *(int4*)(wdst0 + 4096) = pk0; *(int4*)(wdst1 + 4096) = pk1;
  LOADA(2, 0) LOADA(3, 1)
  CVTA(0)  // pk = A(2)
  // vmcnt(8): newest 8 = A(2)+A(3) reg loads -> B(0),B(1) DMA guaranteed landed
  asm volatile("s_waitcnt lgkmcnt(0) vmcnt(8)\n\ts_barrier" ::: "memory");

  for (int tt = 0; tt < NT; tt += 2) {
    QKBODY(tt, 0, 1)
    QKBODY(tt + 1, 1, 0)
  }

  // epilogue: bias + bf16 store; optional fused row-norm scores (wave's 64 cols = 1 head)
  float bs[4];
#pragma unroll
  for (int j = 0; j < 4; j++) bs[j] = bias[nt + 64 * wn + 16 * j + l15];
#pragma unroll
  for (int i = 0; i < 4; i++) {
#pragma unroll
    for (int r = 0; r < 4; r++) {
      const int gm = mt + 64 * wm + 16 * i + quad * 4 + r;
      float nrm = 0.f;
#pragma unroll
      for (int j = 0; j < 4; j++) {
        float v = acc[i][j][r] + bs[j];
        Cb[(size_t)gm * EE + (nt + 64 * wn + 16 * j + l15)] = f2b(v);
        nrm += v * v;
      }
      if (scA) {
#pragma unroll
        for (int m = 1; m < 16; m <<= 1) nrm += __shfl_xor(nrm, m, 64);
        if (l15 == 0) atomicAdd(&scA[gm], sqrtf(nrm) * (1.f / 16.f));
      }
    }
  }
}

// ---------------- stage-1 topk: exact top-96 set per batch (order-free) ----------------
#define TKT 1024
#define EQCAP 256
__global__ __launch_bounds__(TKT) void topk1_k(const float* __restrict__ sc, int* __restrict__ cand) {
  const int b = blockIdx.x;
  __shared__ uint32_t s[SS];
  __shared__ int wsum[TKT / 64];
  __shared__ int cnt_sh;
  __shared__ int counter, eqcount;
  __shared__ int eqbuf[EQCAP];
  const int tid = threadIdx.x;
  const int lane = tid & 63, wv = tid >> 6;
  for (int i = tid; i < SS; i += TKT) s[i] = __float_as_uint(sc[b * SS + i]);
  if (tid == 0) { counter = 0; eqcount = 0; }
  __syncthreads();

  uint32_t lo = 0u, hi = 0x7f7fffffu;
  while (lo < hi) {
    uint32_t mid = lo + ((hi - lo + 1) >> 1);
    int c = 0;
    for (int i = tid; i < SS; i += TKT) c += (s[i] >= mid) ? 1 : 0;
#pragma unroll
    for (int m = 1; m < 64; m <<= 1) c += __shfl_xor(c, m, 64);
    if (lane == 0) wsum[wv] = c;
    __syncthreads();
    if (tid == 0) {
      int t = 0;
#pragma unroll
      for (int w = 0; w < TKT / 64; w++) t += wsum[w];
      cnt_sh = t;
    }
    __syncthreads();
    if (cnt_sh >= CANDN) lo = mid; else hi = mid - 1;
    __syncthreads();
  }
  const uint32_t T = lo;  // count(u>T) < CANDN <= count(u>=T)

  for (int i = tid; i < SS; i += TKT) {
    uint32_t u = s[i];
    if (u > T) {
      int p = atomicAdd(&counter, 1);
      cand[b * CANDN + p] = i;
    } else if (u == T) {
      int p = atomicAdd(&eqcount, 1);
      if (p < EQCAP) eqbuf[p] = i;
    }
  }
  __syncthreads();
  const int above = counter;
  const int rem = CANDN - above;
  int ec = eqcount; if (ec > EQCAP) ec = EQCAP;
  __syncthreads();
  for (int i = tid; i < ec; i += TKT) {
    int me = eqbuf[i];
    int rank = 0;
    for (int j = 0; j < ec; j++) rank += (eqbuf[j] < me) ? 1 : 0;
    if (rank < rem) {
      int p = atomicAdd(&counter, 1);
      cand[b * CANDN + p] = me;
    }
  }
}

// ---------------- stage-2: exact fp64 k for candidates ----------------
__global__ __launch_bounds__(256) void rescore_k(const float* __restrict__ key, const float* __restrict__ Wk,
                                                 const int* __restrict__ cand, double* __restrict__ kpart) {
  const int kc = blockIdx.x, h = blockIdx.y, b = blockIdx.z;
  const int d = threadIdx.x & 63, cg = threadIdx.x >> 6;
  __shared__ float wk[64 * 257];   // padded: 64 rows stride 257
  __shared__ float xs[24 * 256];
  for (int i = threadIdx.x; i < 64 * 256; i += 256)
    wk[(i >> 8) * 257 + (i & 255)] = Wk[(size_t)(h * 64 + (i >> 8)) * EE + kc * 256 + (i & 255)];
  for (int c0 = 0; c0 < CANDN; c0 += 24) {
    __syncthreads();
    for (int i = threadIdx.x; i < 24 * 256; i += 256) {
      int c = c0 + (i >> 8);
      xs[i] = key[((size_t)b * SS + cand[b * CANDN + c]) * EE + kc * 256 + (i & 255)];
    }
    __syncthreads();
    double acc[6] = {0, 0, 0, 0, 0, 0};
    for (int kk = 0; kk < 256; kk++) {
      double wv_ = (double)wk[d * 257 + kk];
#pragma unroll
      for (int j = 0; j < 6; j++)
        acc[j] += wv_ * (double)xs[(cg * 6 + j) * 256 + kk];
    }
#pragma unroll
    for (int j = 0; j < 6; j++) {
      int c = c0 + cg * 6 + j;
      kpart[(((size_t)kc * BB + b) * CANDN + c) * 1024 + h * 64 + d] = acc[j];
    }
  }
}

// exact fp64 candidate scores
__global__ __launch_bounds__(64) void score2_k(const double* __restrict__ kpart, const float* __restrict__ bk,
                                               double* __restrict__ sc2) {
  const int c = blockIdx.x, b = blockIdx.y;
  const int lane = threadIdx.x;
  double tot = 0.0;
  for (int h = 0; h < HH; h++) {
    double v = (double)bk[h * 64 + lane];
#pragma unroll
    for (int kc = 0; kc < 4; kc++)
      v += kpart[(((size_t)kc * BB + b) * CANDN + c) * 1024 + h * 64 + lane];
    double s = v * v;
#pragma unroll
    for (int m = 1; m < 64; m <<= 1) s += __shfl_xor(s, m, 64);
    tot += sqrt(s);
  }
  if (lane == 0) sc2[b * CANDN + c] = tot * (1.0 / 16.0);
}

// exact rank among candidates -> final idx in descending order (tie: lower index first)
__global__ __launch_bounds__(128) void topk2_k(const double* __restrict__ sc2, const int* __restrict__ cand,
                                               int* __restrict__ idxf) {
  const int b = blockIdx.x, t = threadIdx.x;
  if (t >= CANDN) return;
  double my = sc2[b * CANDN + t];
  int mi = cand[b * CANDN + t];
  int rank = 0;
  for (int j = 0; j < CANDN; j++) {
    double sj = sc2[b * CANDN + j];
    int ij = cand[b * CANDN + j];
    if (sj > my || (sj == my && ij < mi)) rank++;
  }
  if (rank < LL) idxf[b * LL + rank] = mi;
}

// gather value rows for the selected indices (fp32 -> bf16)
__global__ __launch_bounds__(256) void gatherx_k(const float* __restrict__ value, const int* __restrict__ idxf,
                                                 u16* __restrict__ xg) {
  const int r = blockIdx.x;  // b*64 + l
  const int b = r >> 6;
  const float* src = value + ((size_t)b * SS + idxf[r]) * EE;
  for (int i = threadIdx.x; i < EE; i += 256) xg[(size_t)r * EE + i] = f2b(src[i]);
}

// build k_sp[(b,h),l,d] (bf16) and v_spT[(b,h),d,l] (bf16)
__global__ __launch_bounds__(64) void gathersp_k(const u16* __restrict__ kb, const float* __restrict__ vg,
                                                 const int* __restrict__ idxf,
                                                 u16* __restrict__ ksp, u16* __restrict__ vspT) {
  const int g = blockIdx.x;  // (b*16+h)*64 + l
  const int l = g & 63, h = (g >> 6) & 15, b = g >> 10;
  const int d = threadIdx.x;
  ksp[(size_t)g * 64 + d] = kb[((size_t)b * SS + idxf[b * 64 + l]) * EE + h * 64 + d];
  vspT[((size_t)(b * 16 + h) * 64 + d) * 64 + l] = f2b(vg[((size_t)b * 64 + l) * EE + h * 64 + d]);
}

// ---------------- fused attention: QK^T -> softmax -> w out -> PV -> attn out ----------------
__global__ __launch_bounds__(256) void attn_k(const u16* __restrict__ qb, const u16* __restrict__ ksp,
                                              const u16* __restrict__ vspT,
                                              float* __restrict__ wout, u16* __restrict__ attnb) {
  __shared__ __align__(16) u16 qt[4096];
  __shared__ __align__(16) u16 kt[4096];
  __shared__ __align__(16) u16 vt[4096];
  __shared__ __align__(16) u16 wt[4096];
  const int tid = threadIdx.x;
  const int wv = tid >> 6, lane = tid & 63, quad = lane >> 4, l15 = lane & 15;
  const int s0 = blockIdx.x * 64;
  const int bh = blockIdx.y, b = bh >> 4, h = bh & 15;

  {
    const int bi0 = tid, bi1 = 256 + tid;
    const int r0 = bi0 >> 3, c0 = (bi0 & 7) ^ (r0 & 7);
    const int r1 = bi1 >> 3, c1 = (bi1 & 7) ^ (r1 & 7);
    const u16* qg = qb + ((size_t)b * SS + s0) * EE + h * 64;
    async16(qg + (size_t)r0 * EE + c0 * 8, qt + bi0 * 8);
    async16(qg + (size_t)r1 * EE + c1 * 8, qt + bi1 * 8);
    const u16* kg = ksp + (size_t)bh * 4096;
    async16(kg + r0 * 64 + c0 * 8, kt + bi0 * 8);
    async16(kg + r1 * 64 + c1 * 8, kt + bi1 * 8);
    const u16* vgp = vspT + (size_t)bh * 4096;
    async16(vgp + r0 * 64 + c0 * 8, vt + bi0 * 8);
    async16(vgp + r1 * 64 + c1 * 8, vt + bi1 * 8);
  }
  __syncthreads();

  f32x4 acc[4];
#pragma unroll
  for (int j = 0; j < 4; j++) acc[j] = (f32x4){0.f, 0.f, 0.f, 0.f};
  const int ar = 16 * wv + l15;
#pragma unroll
  for (int ks = 0; ks < 2; ks++) {
    const int cg = quad + ks * 4;
    short8 af = ((const short8*)qt)[ar * 8 + (cg ^ (ar & 7))];
#pragma unroll
    for (int j = 0; j < 4; j++) {
      int br = 16 * j + l15;
      short8 bf = ((const short8*)kt)[br * 8 + (cg ^ (br & 7))];
      acc[j] = __builtin_amdgcn_mfma_f32_16x16x32_bf16(af, bf, acc[j], 0, 0, 0);
    }
  }
#pragma unroll
  for (int j = 0; j < 4; j++) acc[j] *= 0.125f;  // 1/sqrt(D)

  float inv[4];
#pragma unroll
  for (int r = 0; r < 4; r++) {
    float m = fmaxf(fmaxf(acc[0][r], acc[1][r]), fmaxf(acc[2][r], acc[3][r]));
#pragma unroll
    for (int msk = 1; msk < 16; msk <<= 1) m = fmaxf(m, __shfl_xor(m, msk, 64));
    float e0 = __expf(acc[0][r] - m);
    float e1 = __expf(acc[1][r] - m);
    float e2 = __expf(acc[2][r] - m);
    float e3 = __expf(acc[3][r] - m);
    acc[0][r] = e0; acc[1][r] = e1; acc[2][r] = e2; acc[3][r] = e3;
    float s = e0 + e1 + e2 + e3;
#pragma unroll
    for (int msk = 1; msk < 16; msk <<= 1) s += __shfl_xor(s, msk, 64);
    inv[r] = 1.f / s;
  }

  const size_t wbase = ((size_t)bh * SS + s0 + 16 * wv) * 64;
#pragma unroll
  for (int j = 0; j < 4; j++) {
#pragma unroll
    for (int r = 0; r < 4; r++) {
      float val = acc[j][r] * inv[r];
      int rowl = quad * 4 + r;
      int l = 16 * j + l15;
      wout[wbase + (size_t)rowl * 64 + l] = val;
      int wr = 16 * wv + rowl;
      wt[wr * 64 + ((l >> 3) ^ (wr & 7)) * 8 + (l & 7)] = f2b(val);
    }
  }
  __syncthreads();

  f32x4 acc2[4];
#pragma unroll
  for (int j = 0; j < 4; j++) acc2[j] = (f32x4){0.f, 0.f, 0.f, 0.f};
#pragma unroll
  for (int ks = 0; ks < 2; ks++) {
    const int cg = quad + ks * 4;
    short8 af = ((const short8*)wt)[ar * 8 + (cg ^ (ar & 7))];
#pragma unroll
    for (int j = 0; j < 4; j++) {
      int br = 16 * j + l15;
      short8 bf = ((const short8*)vt)[br * 8 + (cg ^ (br & 7))];
      acc2[j] = __builtin_amdgcn_mfma_f32_16x16x32_bf16(af, bf, acc2[j], 0, 0, 0);
    }
  }
#pragma unroll
  for (int j = 0; j < 4; j++)
#pragma unroll
    for (int r = 0; r < 4; r++)
      attnb[((size_t)b * SS + s0 + 16 * wv + quad * 4 + r) * EE + h * 64 + 16 * j + l15] = f2b(acc2[j][r]);
}

extern "C" void kernel_launch(void* const* d_in, const int* in_sizes, int n_in,
                              void* d_out, int out_size, void* d_ws, size_t ws_size,
                              hipStream_t stream) {
  (void)in_sizes; (void)n_in; (void)out_size; (void)ws_size;
  const float* query = (const float*)d_in[0];
  const float* key   = (const float*)d_in[1];
  const float* value = (const float*)d_in[2];
  const float* Wq = (const float*)d_in[3];
  const float* bq = (const float*)d_in[4];
  const float* Wk = (const float*)d_in[5];
  const float* bk = (const float*)d_in[6];
  const float* Wv = (const float*)d_in[7];
  const float* bv = (const float*)d_in[8];
  const float* Wo = (const float*)d_in[9];
  const float* bo = (const float*)d_in[10];
  float* out = (float*)d_out;
  float* wout = out + (size_t)BB * SS * EE;

  char* p = (char*)d_ws;
  auto alloc = [&](size_t n) { char* r = p; p += (n + 255) & ~(size_t)255; return r; };
  u16* qbf = (u16*)alloc((size_t)BB * SS * EE * 2);   // reused as attn output buffer
  u16* kbf = (u16*)alloc((size_t)BB * SS * EE * 2);   // (unused; kept for layout stability)
  u16* wqb = (u16*)alloc((size_t)EE * EE * 2);
  u16* wkb = (u16*)alloc((size_t)EE * EE * 2);
  u16* wvb = (u16*)alloc((size_t)EE * EE * 2);
  u16* wob = (u16*)alloc((size_t)EE * EE * 2);
  u16* qb  = (u16*)alloc((size_t)BB * SS * EE * 2);
  u16* kb  = (u16*)alloc((size_t)BB * SS * EE * 2);
  float*  sc    = (float*)alloc((size_t)BB * SS * 4);
  int*    cand  = (int*)alloc(BB * CANDN * 4);
  double* kpart = (double*)alloc((size_t)4 * BB * CANDN * 1024 * 8);
  double* sc2   = (double*)alloc(BB * CANDN * 8);
  int*    idxf  = (int*)alloc(BB * LL * 4);
  u16*    xg    = (u16*)alloc((size_t)BB * LL * EE * 2);
  float*  vg    = (float*)alloc((size_t)BB * LL * EE * 4);
  u16*    ksp   = (u16*)alloc((size_t)BB * HH * LL * DD * 2);
  u16*    vspT  = (u16*)alloc((size_t)BB * HH * DD * LL * 2);
  u16*    attnb = qbf;  // reuse

  const int M = BB * SS;
  const size_t gemm_lds = 98304;  // gemm256: 2*(256*64 + 128*64) u16

  cvt_bf16_k<<<(EE * EE / 4 + 255) / 256, 256, 0, stream>>>(Wq, wqb, EE * EE / 4);
  cvt_bf16_k<<<(EE * EE / 4 + 255) / 256, 256, 0, stream>>>(Wk, wkb, EE * EE / 4);
  cvt_bf16_k<<<(EE * EE / 4 + 255) / 256, 256, 0, stream>>>(Wv, wvb, EE * EE / 4);
  cvt_bf16_k<<<(EE * EE / 4 + 255) / 256, 256, 0, stream>>>(Wo, wob, EE * EE / 4);
  hipMemsetAsync(sc, 0, (size_t)M * 4, stream);

  dim3 gq(EE / 128, M / 128);
  gemm_qk<<<gq, 256, 0, stream>>>(query, wqb, bq, qb, nullptr, EE);  // Q proj (fused cvt)
  gemm_qk<<<gq, 256, 0, stream>>>(key, wkb, bk, kb, sc, EE);         // K proj + fused scores

  topk1_k<<<BB, TKT, 0, stream>>>(sc, cand);
  rescore_k<<<dim3(4, HH, BB), 256, 0, stream>>>(key, Wk, cand, kpart);
  score2_k<<<dim3(CANDN, BB), 64, 0, stream>>>(kpart, bk, sc2);
  topk2_k<<<BB, 128, 0, stream>>>(sc2, cand, idxf);

  gatherx_k<<<BB * LL, 256, 0, stream>>>(value, idxf, xg);
  gemm256<<<dim3(EE / 128, BB * LL / 256), 512, gemm_lds, stream>>>(xg, wvb, bv, vg, nullptr, EE);  // V on 256 rows
  gathersp_k<<<BB * HH * LL, 64, 0, stream>>>(kb, vg, idxf, ksp, vspT);

  attn_k<<<dim3(SS / 64, BB * HH), 256, 0, stream>>>(qb, ksp, vspT, wout, attnb);

  gemm256<<<dim3(EE / 128, M / 256), 512, gemm_lds, stream>>>(attnb, wob, bo, out, nullptr, EE); // output projection
}

// Round 8
// 979.771 us; speedup vs baseline: 2.3931x; 1.0439x over previous
//
#include <hip/hip_runtime.h>
#include <cstdint>

typedef unsigned short u16;
typedef __attribute__((ext_vector_type(8))) short short8;
typedef __attribute__((ext_vector_type(4))) float f32x4;

#define AS1 __attribute__((address_space(1)))
#define AS3 __attribute__((address_space(3)))

#define BB 4
#define SS 8192
#define EE 1024
#define HH 16
#define DD 64
#define LL 64
#define CANDN 96

__device__ __forceinline__ void async16(const void* g, void* l) {
  __builtin_amdgcn_global_load_lds((const AS1 uint32_t*)g, (AS3 uint32_t*)l, 16, 0, 0);
}
__device__ __forceinline__ u16 f2b(float f) {  // RNE fp32 -> bf16
  uint32_t u = __float_as_uint(f);
  return (u16)((u + 0x7fffu + ((u >> 16) & 1u)) >> 16);
}
__device__ __forceinline__ float b2f(u16 h) { return __uint_as_float(((uint32_t)h) << 16); }

// ---------------- fp32 -> bf16 bulk convert (n divisible by 4) ----------------
__global__ __launch_bounds__(256) void cvt_bf16_k(const float* __restrict__ in, u16* __restrict__ out, int n4) {
  int i = blockIdx.x * 256 + threadIdx.x;
  if (i >= n4) return;
  float4 v = ((const float4*)in)[i];
  ushort4 o;
  o.x = f2b(v.x); o.y = f2b(v.y); o.z = f2b(v.z); o.w = f2b(v.w);
  ((ushort4*)out)[i] = o;
}

#define FENCE_RW()  asm volatile("s_waitcnt lgkmcnt(0)\n\ts_barrier" ::: "memory")
#define FENCE_V6()  asm volatile("s_waitcnt vmcnt(6)\n\ts_barrier" ::: "memory")
#define FENCE_V0()  asm volatile("s_waitcnt vmcnt(0)\n\ts_barrier" ::: "memory")

// ---------------- NT GEMM v2 (bf16 A): C[m,n] = sum_k A[m,k]*W[n,k] + bias[n] ----------------
// Tile 256x128, BK=64, 512 threads = 8 waves (4m x 2n), acc[4][4]/wave. Counted-vmcnt
// pipeline; LDS granule-XOR swizzle g^(row&7) applied on the pre-swizzled global SOURCE.
// Optional scA epilogue (K-projection): per row, per head (wave's 64 cols = 1 head),
// 16-lane shuffle-reduce of sum((v+bias)^2), one atomicAdd(sqrt/16) -> replaces scores_k.
// (R7 post-mortem: fused-fp32-A gemm_qk measured 164-179us vs this structure's ~52-70us;
// reverted to cvt + gemm256, keeping only the free scores fusion.)
__global__ __launch_bounds__(512) void gemm256(const u16* __restrict__ A, const u16* __restrict__ W,
                                               const float* __restrict__ bias,
                                               float* __restrict__ Cf, u16* __restrict__ Cb,
                                               float* __restrict__ scA, int K) {
  extern __shared__ __align__(16) u16 lds_[];
  u16* lA = lds_;            // [2][256*64]
  u16* lB = lds_ + 32768;    // [2][128*64]
  const int tid = threadIdx.x;
  const int wv = tid >> 6, lane = tid & 63;
  const int quad = lane >> 4, l15 = lane & 15;
  const int wm = wv >> 1, wn = wv & 1;   // 4 x 2 waves; per-wave out 64x64

  const int nwg = gridDim.x * gridDim.y;
  int g = blockIdx.y * gridDim.x + blockIdx.x;
  int bx = blockIdx.x, by = blockIdx.y;
  if ((nwg & 7) == 0) {
    const int chunk = nwg >> 3;
    const int v = (g & 7) * chunk + (g >> 3);
    bx = v % gridDim.x;
    by = v / gridDim.x;
  }
  const int mt = by * 256, nt = bx * 128;

  const int rl = tid >> 3;
  const int g8 = (((tid & 7) ^ (rl & 7))) * 8;
  const u16* sA00 = A + (size_t)(mt + rl) * K + g8;
  const u16* sA01 = A + (size_t)(mt + 64 + rl) * K + g8;
  const u16* sA10 = A + (size_t)(mt + 128 + rl) * K + g8;
  const u16* sA11 = A + (size_t)(mt + 192 + rl) * K + g8;
  const u16* sB0  = W + (size_t)(nt + rl) * K + g8;
  const u16* sB1  = W + (size_t)(nt + 64 + rl) * K + g8;
  const int dA = tid * 8;
  const int dB = tid * 8;

  auto STAGE = [&](int tile, int pb) {
    const int off = tile * 64;
    async16(sA00 + off, lA + pb * 16384 + dA);
    async16(sA01 + off, lA + pb * 16384 + dA + 4096);
    async16(sA10 + off, lA + pb * 16384 + 8192 + dA);
    async16(sA11 + off, lA + pb * 16384 + 8192 + dA + 4096);
    async16(sB0 + off, lB + pb * 8192 + dB);
    async16(sB1 + off, lB + pb * 8192 + dB + 4096);
  };

  f32x4 acc[4][4];
#pragma unroll
  for (int i = 0; i < 4; i++)
#pragma unroll
    for (int j = 0; j < 4; j++) acc[i][j] = (f32x4){0.f, 0.f, 0.f, 0.f};

  const int NT = K >> 6;
  STAGE(0, 0);
  STAGE(1, 1);
  FENCE_V6();  // tile0's 6 landed; tile1's 6 in flight

  for (int t = 0; t < NT; ++t) {
    const int pb = t & 1;
    const short8* pA = (const short8*)(lA + pb * 16384);
    const short8* pB = (const short8*)(lB + pb * 8192);
    short8 af[2][4], bf[2][4];
#pragma unroll
    for (int i = 0; i < 4; i++) {
      const int r = 64 * wm + 16 * i + l15;
      af[0][i] = pA[r * 8 + (quad ^ (r & 7))];
      af[1][i] = pA[r * 8 + ((quad + 4) ^ (r & 7))];
      const int rb = 64 * wn + 16 * i + l15;
      bf[0][i] = pB[rb * 8 + (quad ^ (rb & 7))];
      bf[1][i] = pB[rb * 8 + ((quad + 4) ^ (rb & 7))];
    }
#pragma unroll
    for (int i = 0; i < 4; i++)
#pragma unroll
      for (int j = 0; j < 4; j++)
        acc[i][j] = __builtin_amdgcn_mfma_f32_16x16x32_bf16(af[0][i], bf[0][j], acc[i][j], 0, 0, 0);
    FENCE_RW();                       // all reads of buf[pb] retired before DMA may land
    if (t + 2 < NT) STAGE(t + 2, pb); // overwrite just-freed buffer
#pragma unroll
    for (int i = 0; i < 4; i++)
#pragma unroll
      for (int j = 0; j < 4; j++)
        acc[i][j] = __builtin_amdgcn_mfma_f32_16x16x32_bf16(af[1][i], bf[1][j], acc[i][j], 0, 0, 0);
    if (t + 1 < NT) {
      if (t + 1 == NT - 1) { FENCE_V0(); } else { FENCE_V6(); }
    }
  }

  float bs[4];
#pragma unroll
  for (int j = 0; j < 4; j++) bs[j] = bias[nt + 64 * wn + 16 * j + l15];
#pragma unroll
  for (int i = 0; i < 4; i++) {
#pragma unroll
    for (int r = 0; r < 4; r++) {
      const int gm = mt + 64 * wm + 16 * i + quad * 4 + r;
      float nrm = 0.f;
#pragma unroll
      for (int j = 0; j < 4; j++) {
        float v = acc[i][j][r] + bs[j];
        const int gn = nt + 64 * wn + 16 * j + l15;
        if (Cf) Cf[(size_t)gm * EE + gn] = v;
        if (Cb) Cb[(size_t)gm * EE + gn] = f2b(v);
        nrm += v * v;
      }
      if (scA) {
#pragma unroll
        for (int m = 1; m < 16; m <<= 1) nrm += __shfl_xor(nrm, m, 64);
        if (l15 == 0) atomicAdd(&scA[gm], sqrtf(nrm) * (1.f / 16.f));
      }
    }
  }
}

// ---------------- stage-1 topk: exact top-96 set per batch (order-free) ----------------
#define TKT 1024
#define EQCAP 256
__global__ __launch_bounds__(TKT) void topk1_k(const float* __restrict__ sc, int* __restrict__ cand) {
  const int b = blockIdx.x;
  __shared__ uint32_t s[SS];
  __shared__ int wsum[TKT / 64];
  __shared__ int cnt_sh;
  __shared__ int counter, eqcount;
  __shared__ int eqbuf[EQCAP];
  const int tid = threadIdx.x;
  const int lane = tid & 63, wv = tid >> 6;
  for (int i = tid; i < SS; i += TKT) s[i] = __float_as_uint(sc[b * SS + i]);
  if (tid == 0) { counter = 0; eqcount = 0; }
  __syncthreads();

  uint32_t lo = 0u, hi = 0x7f7fffffu;
  while (lo < hi) {
    uint32_t mid = lo + ((hi - lo + 1) >> 1);
    int c = 0;
    for (int i = tid; i < SS; i += TKT) c += (s[i] >= mid) ? 1 : 0;
#pragma unroll
    for (int m = 1; m < 64; m <<= 1) c += __shfl_xor(c, m, 64);
    if (lane == 0) wsum[wv] = c;
    __syncthreads();
    if (tid == 0) {
      int t = 0;
#pragma unroll
      for (int w = 0; w < TKT / 64; w++) t += wsum[w];
      cnt_sh = t;
    }
    __syncthreads();
    if (cnt_sh >= CANDN) lo = mid; else hi = mid - 1;
    __syncthreads();
  }
  const uint32_t T = lo;  // count(u>T) < CANDN <= count(u>=T)

  for (int i = tid; i < SS; i += TKT) {
    uint32_t u = s[i];
    if (u > T) {
      int p = atomicAdd(&counter, 1);
      cand[b * CANDN + p] = i;
    } else if (u == T) {
      int p = atomicAdd(&eqcount, 1);
      if (p < EQCAP) eqbuf[p] = i;
    }
  }
  __syncthreads();
  const int above = counter;
  const int rem = CANDN - above;
  int ec = eqcount; if (ec > EQCAP) ec = EQCAP;
  __syncthreads();
  for (int i = tid; i < ec; i += TKT) {
    int me = eqbuf[i];
    int rank = 0;
    for (int j = 0; j < ec; j++) rank += (eqbuf[j] < me) ? 1 : 0;
    if (rank < rem) {
      int p = atomicAdd(&counter, 1);
      cand[b * CANDN + p] = me;
    }
  }
}

// ---------------- stage-2: exact fp64 k for candidates ----------------
__global__ __launch_bounds__(256) void rescore_k(const float* __restrict__ key, const float* __restrict__ Wk,
                                                 const int* __restrict__ cand, double* __restrict__ kpart) {
  const int kc = blockIdx.x, h = blockIdx.y, b = blockIdx.z;
  const int d = threadIdx.x & 63, cg = threadIdx.x >> 6;
  __shared__ float wk[64 * 257];   // padded: 64 rows stride 257
  __shared__ float xs[24 * 256];
  for (int i = threadIdx.x; i < 64 * 256; i += 256)
    wk[(i >> 8) * 257 + (i & 255)] = Wk[(size_t)(h * 64 + (i >> 8)) * EE + kc * 256 + (i & 255)];
  for (int c0 = 0; c0 < CANDN; c0 += 24) {
    __syncthreads();
    for (int i = threadIdx.x; i < 24 * 256; i += 256) {
      int c = c0 + (i >> 8);
      xs[i] = key[((size_t)b * SS + cand[b * CANDN + c]) * EE + kc * 256 + (i & 255)];
    }
    __syncthreads();
    double acc[6] = {0, 0, 0, 0, 0, 0};
    for (int kk = 0; kk < 256; kk++) {
      double wv_ = (double)wk[d * 257 + kk];
#pragma unroll
      for (int j = 0; j < 6; j++)
        acc[j] += wv_ * (double)xs[(cg * 6 + j) * 256 + kk];
    }
#pragma unroll
    for (int j = 0; j < 6; j++) {
      int c = c0 + cg * 6 + j;
      kpart[(((size_t)kc * BB + b) * CANDN + c) * 1024 + h * 64 + d] = acc[j];
    }
  }
}

// exact fp64 candidate scores
__global__ __launch_bounds__(64) void score2_k(const double* __restrict__ kpart, const float* __restrict__ bk,
                                               double* __restrict__ sc2) {
  const int c = blockIdx.x, b = blockIdx.y;
  const int lane = threadIdx.x;
  double tot = 0.0;
  for (int h = 0; h < HH; h++) {
    double v = (double)bk[h * 64 + lane];
#pragma unroll
    for (int kc = 0; kc < 4; kc++)
      v += kpart[(((size_t)kc * BB + b) * CANDN + c) * 1024 + h * 64 + lane];
    double s = v * v;
#pragma unroll
    for (int m = 1; m < 64; m <<= 1) s += __shfl_xor(s, m, 64);
    tot += sqrt(s);
  }
  if (lane == 0) sc2[b * CANDN + c] = tot * (1.0 / 16.0);
}

// exact rank among candidates -> final idx in descending order (tie: lower index first)
__global__ __launch_bounds__(128) void topk2_k(const double* __restrict__ sc2, const int* __restrict__ cand,
                                               int* __restrict__ idxf) {
  const int b = blockIdx.x, t = threadIdx.x;
  if (t >= CANDN) return;
  double my = sc2[b * CANDN + t];
  int mi = cand[b * CANDN + t];
  int rank = 0;
  for (int j = 0; j < CANDN; j++) {
    double sj = sc2[b * CANDN + j];
    int ij = cand[b * CANDN + j];
    if (sj > my || (sj == my && ij < mi)) rank++;
  }
  if (rank < LL) idxf[b * LL + rank] = mi;
}

// gather value rows for the selected indices (fp32 -> bf16)
__global__ __launch_bounds__(256) void gatherx_k(const float* __restrict__ value, const int* __restrict__ idxf,
                                                 u16* __restrict__ xg) {
  const int r = blockIdx.x;  // b*64 + l
  const int b = r >> 6;
  const float* src = value + ((size_t)b * SS + idxf[r]) * EE;
  for (int i = threadIdx.x; i < EE; i += 256) xg[(size_t)r * EE + i] = f2b(src[i]);
}

// build k_sp[(b,h),l,d] (bf16) and v_spT[(b,h),d,l] (bf16)
__global__ __launch_bounds__(64) void gathersp_k(const u16* __restrict__ kb, const float* __restrict__ vg,
                                                 const int* __restrict__ idxf,
                                                 u16* __restrict__ ksp, u16* __restrict__ vspT) {
  const int g = blockIdx.x;  // (b*16+h)*64 + l
  const int l = g & 63, h = (g >> 6) & 15, b = g >> 10;
  const int d = threadIdx.x;
  ksp[(size_t)g * 64 + d] = kb[((size_t)b * SS + idxf[b * 64 + l]) * EE + h * 64 + d];
  vspT[((size_t)(b * 16 + h) * 64 + d) * 64 + l] = f2b(vg[((size_t)b * 64 + l) * EE + h * 64 + d]);
}

// ---------------- fused attention: QK^T -> softmax -> w out -> PV -> attn out ----------------
__global__ __launch_bounds__(256) void attn_k(const u16* __restrict__ qb, const u16* __restrict__ ksp,
                                              const u16* __restrict__ vspT,
                                              float* __restrict__ wout, u16* __restrict__ attnb) {
  __shared__ __align__(16) u16 qt[4096];
  __shared__ __align__(16) u16 kt[4096];
  __shared__ __align__(16) u16 vt[4096];
  __shared__ __align__(16) u16 wt[4096];
  const int tid = threadIdx.x;
  const int wv = tid >> 6, lane = tid & 63, quad = lane >> 4, l15 = lane & 15;
  const int s0 = blockIdx.x * 64;
  const int bh = blockIdx.y, b = bh >> 4, h = bh & 15;

  {
    const int bi0 = tid, bi1 = 256 + tid;
    const int r0 = bi0 >> 3, c0 = (bi0 & 7) ^ (r0 & 7);
    const int r1 = bi1 >> 3, c1 = (bi1 & 7) ^ (r1 & 7);
    const u16* qg = qb + ((size_t)b * SS + s0) * EE + h * 64;
    async16(qg + (size_t)r0 * EE + c0 * 8, qt + bi0 * 8);
    async16(qg + (size_t)r1 * EE + c1 * 8, qt + bi1 * 8);
    const u16* kg = ksp + (size_t)bh * 4096;
    async16(kg + r0 * 64 + c0 * 8, kt + bi0 * 8);
    async16(kg + r1 * 64 + c1 * 8, kt + bi1 * 8);
    const u16* vgp = vspT + (size_t)bh * 4096;
    async16(vgp + r0 * 64 + c0 * 8, vt + bi0 * 8);
    async16(vgp + r1 * 64 + c1 * 8, vt + bi1 * 8);
  }
  __syncthreads();

  f32x4 acc[4];
#pragma unroll
  for (int j = 0; j < 4; j++) acc[j] = (f32x4){0.f, 0.f, 0.f, 0.f};
  const int ar = 16 * wv + l15;
#pragma unroll
  for (int ks = 0; ks < 2; ks++) {
    const int cg = quad + ks * 4;
    short8 af = ((const short8*)qt)[ar * 8 + (cg ^ (ar & 7))];
#pragma unroll
    for (int j = 0; j < 4; j++) {
      int br = 16 * j + l15;
      short8 bf = ((const short8*)kt)[br * 8 + (cg ^ (br & 7))];
      acc[j] = __builtin_amdgcn_mfma_f32_16x16x32_bf16(af, bf, acc[j], 0, 0, 0);
    }
  }
#pragma unroll
  for (int j = 0; j < 4; j++) acc[j] *= 0.125f;  // 1/sqrt(D)

  float inv[4];
#pragma unroll
  for (int r = 0; r < 4; r++) {
    float m = fmaxf(fmaxf(acc[0][r], acc[1][r]), fmaxf(acc[2][r], acc[3][r]));
#pragma unroll
    for (int msk = 1; msk < 16; msk <<= 1) m = fmaxf(m, __shfl_xor(m, msk, 64));
    float e0 = __expf(acc[0][r] - m);
    float e1 = __expf(acc[1][r] - m);
    float e2 = __expf(acc[2][r] - m);
    float e3 = __expf(acc[3][r] - m);
    acc[0][r] = e0; acc[1][r] = e1; acc[2][r] = e2; acc[3][r] = e3;
    float s = e0 + e1 + e2 + e3;
#pragma unroll
    for (int msk = 1; msk < 16; msk <<= 1) s += __shfl_xor(s, msk, 64);
    inv[r] = 1.f / s;
  }

  const size_t wbase = ((size_t)bh * SS + s0 + 16 * wv) * 64;
#pragma unroll
  for (int j = 0; j < 4; j++) {
#pragma unroll
    for (int r = 0; r < 4; r++) {
      float val = acc[j][r] * inv[r];
      int rowl = quad * 4 + r;
      int l = 16 * j + l15;
      wout[wbase + (size_t)rowl * 64 + l] = val;
      int wr = 16 * wv + rowl;
      wt[wr * 64 + ((l >> 3) ^ (wr & 7)) * 8 + (l & 7)] = f2b(val);
    }
  }
  __syncthreads();

  f32x4 acc2[4];
#pragma unroll
  for (int j = 0; j < 4; j++) acc2[j] = (f32x4){0.f, 0.f, 0.f, 0.f};
#pragma unroll
  for (int ks = 0; ks < 2; ks++) {
    const int cg = quad + ks * 4;
    short8 af = ((const short8*)wt)[ar * 8 + (cg ^ (ar & 7))];
#pragma unroll
    for (int j = 0; j < 4; j++) {
      int br = 16 * j + l15;
      short8 bf = ((const short8*)vt)[br * 8 + (cg ^ (br & 7))];
      acc2[j] = __builtin_amdgcn_mfma_f32_16x16x32_bf16(af, bf, acc2[j], 0, 0, 0);
    }
  }
#pragma unroll
  for (int j = 0; j < 4; j++)
#pragma unroll
    for (int r = 0; r < 4; r++)
      attnb[((size_t)b * SS + s0 + 16 * wv + quad * 4 + r) * EE + h * 64 + 16 * j + l15] = f2b(acc2[j][r]);
}

extern "C" void kernel_launch(void* const* d_in, const int* in_sizes, int n_in,
                              void* d_out, int out_size, void* d_ws, size_t ws_size,
                              hipStream_t stream) {
  (void)in_sizes; (void)n_in; (void)out_size; (void)ws_size;
  const float* query = (const float*)d_in[0];
  const float* key   = (const float*)d_in[1];
  const float* value = (const float*)d_in[2];
  const float* Wq = (const float*)d_in[3];
  const float* bq = (const float*)d_in[4];
  const float* Wk = (const float*)d_in[5];
  const float* bk = (const float*)d_in[6];
  const float* Wv = (const float*)d_in[7];
  const float* bv = (const float*)d_in[8];
  const float* Wo = (const float*)d_in[9];
  const float* bo = (const float*)d_in[10];
  float* out = (float*)d_out;
  float* wout = out + (size_t)BB * SS * EE;

  char* p = (char*)d_ws;
  auto alloc = [&](size_t n) { char* r = p; p += (n + 255) & ~(size_t)255; return r; };
  u16* qbf = (u16*)alloc((size_t)BB * SS * EE * 2);   // query bf16; reused later as attn output
  u16* kbf = (u16*)alloc((size_t)BB * SS * EE * 2);
  u16* wqb = (u16*)alloc((size_t)EE * EE * 2);
  u16* wkb = (u16*)alloc((size_t)EE * EE * 2);
  u16* wvb = (u16*)alloc((size_t)EE * EE * 2);
  u16* wob = (u16*)alloc((size_t)EE * EE * 2);
  u16* qb  = (u16*)alloc((size_t)BB * SS * EE * 2);
  u16* kb  = (u16*)alloc((size_t)BB * SS * EE * 2);
  float*  sc    = (float*)alloc((size_t)BB * SS * 4);
  int*    cand  = (int*)alloc(BB * CANDN * 4);
  double* kpart = (double*)alloc((size_t)4 * BB * CANDN * 1024 * 8);
  double* sc2   = (double*)alloc(BB * CANDN * 8);
  int*    idxf  = (int*)alloc(BB * LL * 4);
  u16*    xg    = (u16*)alloc((size_t)BB * LL * EE * 2);
  float*  vg    = (float*)alloc((size_t)BB * LL * EE * 4);
  u16*    ksp   = (u16*)alloc((size_t)BB * HH * LL * DD * 2);
  u16*    vspT  = (u16*)alloc((size_t)BB * HH * DD * LL * 2);
  u16*    attnb = qbf;  // reuse: query_bf16 dead after Q GEMM

  const int M = BB * SS;
  const size_t gemm_lds = 98304;  // 2*(256*64 + 128*64) u16

  cvt_bf16_k<<<(M * EE / 4 + 255) / 256, 256, 0, stream>>>(query, qbf, M * EE / 4);
  cvt_bf16_k<<<(M * EE / 4 + 255) / 256, 256, 0, stream>>>(key, kbf, M * EE / 4);
  cvt_bf16_k<<<(EE * EE / 4 + 255) / 256, 256, 0, stream>>>(Wq, wqb, EE * EE / 4);
  cvt_bf16_k<<<(EE * EE / 4 + 255) / 256, 256, 0, stream>>>(Wk, wkb, EE * EE / 4);
  cvt_bf16_k<<<(EE * EE / 4 + 255) / 256, 256, 0, stream>>>(Wv, wvb, EE * EE / 4);
  cvt_bf16_k<<<(EE * EE / 4 + 255) / 256, 256, 0, stream>>>(Wo, wob, EE * EE / 4);
  hipMemsetAsync(sc, 0, (size_t)M * 4, stream);

  dim3 gg(EE / 128, M / 256);
  gemm256<<<gg, 512, gemm_lds, stream>>>(qbf, wqb, bq, nullptr, qb, nullptr, EE);  // Q projection
  gemm256<<<gg, 512, gemm_lds, stream>>>(kbf, wkb, bk, nullptr, kb, sc, EE);       // K proj + fused scores

  topk1_k<<<BB, TKT, 0, stream>>>(sc, cand);
  rescore_k<<<dim3(4, HH, BB), 256, 0, stream>>>(key, Wk, cand, kpart);
  score2_k<<<dim3(CANDN, BB), 64, 0, stream>>>(kpart, bk, sc2);
  topk2_k<<<BB, 128, 0, stream>>>(sc2, cand, idxf);

  gatherx_k<<<BB * LL, 256, 0, stream>>>(value, idxf, xg);
  gemm256<<<dim3(EE / 128, BB * LL / 256), 512, gemm_lds, stream>>>(xg, wvb, bv, vg, nullptr, nullptr, EE);  // V
  gathersp_k<<<BB * HH * LL, 64, 0, stream>>>(kb, vg, idxf, ksp, vspT);

  attn_k<<<dim3(SS / 64, BB * HH), 256, 0, stream>>>(qb, ksp, vspT, wout, attnb);

  gemm256<<<gg, 512, gemm_lds, stream>>>(attnb, wob, bo, out, nullptr, nullptr, EE); // output projection
}

// Round 9
// 969.923 us; speedup vs baseline: 2.4174x; 1.0102x over previous
//
#include <hip/hip_runtime.h>
#include <cstdint>

typedef unsigned short u16;
typedef __attribute__((ext_vector_type(8))) short short8;
typedef __attribute__((ext_vector_type(4))) float f32x4;

#define AS1 __attribute__((address_space(1)))
#define AS3 __attribute__((address_space(3)))

#define BB 4
#define SS 8192
#define EE 1024
#define HH 16
#define DD 64
#define LL 64
#define CANDN 96

__device__ __forceinline__ void async16(const void* g, void* l) {
  __builtin_amdgcn_global_load_lds((const AS1 uint32_t*)g, (AS3 uint32_t*)l, 16, 0, 0);
}
__device__ __forceinline__ u16 f2b(float f) {  // RNE fp32 -> bf16
  uint32_t u = __float_as_uint(f);
  return (u16)((u + 0x7fffu + ((u >> 16) & 1u)) >> 16);
}
__device__ __forceinline__ float b2f(u16 h) { return __uint_as_float(((uint32_t)h) << 16); }

// ---------------- fp32 -> bf16 bulk convert (n divisible by 4) ----------------
__global__ __launch_bounds__(256) void cvt_bf16_k(const float* __restrict__ in, u16* __restrict__ out, int n4) {
  int i = blockIdx.x * 256 + threadIdx.x;
  if (i >= n4) return;
  float4 v = ((const float4*)in)[i];
  ushort4 o;
  o.x = f2b(v.x); o.y = f2b(v.y); o.z = f2b(v.z); o.w = f2b(v.w);
  ((ushort4*)out)[i] = o;
}

// ---------------- NT GEMM v3 (bf16 A, triple-buffered counted pipeline) ----------------
// C[m,n] = sum_k A[m,k]*W[n,k] + bias[n]. Tile 256x128, BK=64, 512 threads = 8 waves
// (4m x 2n), acc[4][4]/wave. LDS 144 KB = 3 x (256x64 A + 128x64 B) bf16.
// R8 post-mortem: 2-deep dbuf needs a mid-tile lgkmcnt(0)+barrier before re-staging the
// live buffer -> ~530 TF (the 2-phase ceiling, m233). With 3 buffers, tile t+2 stages into
// buf[(t+2)%3] = the buffer consumed at t-1; its reads retired before t-1's closing barrier
// (compiler-inserted lgkmcnt waits before the consuming MFMAs). So the loop carries ONE
// barrier + ONE counted vmcnt per K-tile and never drains vmcnt to 0 mid-loop (T4).
// Ledger: issue t0(6),t1(6) [prologue], then t+2(6) at top of tile t. At each boundary
// outstanding = t+1(rest) + t+2(6, newest); vmcnt completes in issue order (m135), so
// vmcnt(6) -> t+1 landed. t=NT-2 boundary: only t+1's 6 outstanding -> vmcnt(0).
// LDS granule-XOR swizzle g^(row&7) applied on the pre-swizzled global SOURCE (rule #21).
// Optional scA epilogue (K-projection): per row, per head (wave's 64 cols = 1 head),
// 16-lane shuffle-reduce of sum((v+bias)^2), one atomicAdd(sqrt/16) -> replaces scores_k.
__global__ __launch_bounds__(512) void gemm256(const u16* __restrict__ A, const u16* __restrict__ W,
                                               const float* __restrict__ bias,
                                               float* __restrict__ Cf, u16* __restrict__ Cb,
                                               float* __restrict__ scA, int K) {
  extern __shared__ __align__(16) u16 lds_[];
  u16* lA = lds_;              // [3][256*64]
  u16* lB = lds_ + 3 * 16384;  // [3][128*64]
  const int tid = threadIdx.x;
  const int wv = tid >> 6, lane = tid & 63;
  const int quad = lane >> 4, l15 = lane & 15;
  const int wm = wv >> 1, wn = wv & 1;   // 4 x 2 waves; per-wave out 64x64

  const int nwg = gridDim.x * gridDim.y;
  int g = blockIdx.y * gridDim.x + blockIdx.x;
  int bx = blockIdx.x, by = blockIdx.y;
  if ((nwg & 7) == 0) {
    const int chunk = nwg >> 3;
    const int v = (g & 7) * chunk + (g >> 3);
    bx = v % gridDim.x;
    by = v / gridDim.x;
  }
  const int mt = by * 256, nt = bx * 128;

  const int rl = tid >> 3;
  const int g8 = (((tid & 7) ^ (rl & 7))) * 8;
  const u16* sA00 = A + (size_t)(mt + rl) * K + g8;
  const u16* sA01 = A + (size_t)(mt + 64 + rl) * K + g8;
  const u16* sA10 = A + (size_t)(mt + 128 + rl) * K + g8;
  const u16* sA11 = A + (size_t)(mt + 192 + rl) * K + g8;
  const u16* sB0  = W + (size_t)(nt + rl) * K + g8;
  const u16* sB1  = W + (size_t)(nt + 64 + rl) * K + g8;
  const int dA = tid * 8;
  const int dB = tid * 8;

  auto STAGE = [&](int tile, int pb) {
    const int off = tile * 64;
    async16(sA00 + off, lA + pb * 16384 + dA);
    async16(sA01 + off, lA + pb * 16384 + dA + 4096);
    async16(sA10 + off, lA + pb * 16384 + 8192 + dA);
    async16(sA11 + off, lA + pb * 16384 + 8192 + dA + 4096);
    async16(sB0 + off, lB + pb * 8192 + dB);
    async16(sB1 + off, lB + pb * 8192 + dB + 4096);
  };

  f32x4 acc[4][4];
#pragma unroll
  for (int i = 0; i < 4; i++)
#pragma unroll
    for (int j = 0; j < 4; j++) acc[i][j] = (f32x4){0.f, 0.f, 0.f, 0.f};

  const int NT = K >> 6;
  STAGE(0, 0);
  STAGE(1, 1);
  asm volatile("s_waitcnt vmcnt(6)\n\ts_barrier" ::: "memory");  // tile0 landed; tile1 in flight

  int pb = 0;
  for (int t = 0; t < NT; ++t) {
    if (t + 2 < NT) {
      int ps = pb + 2; if (ps >= 3) ps -= 3;
      STAGE(t + 2, ps);                // target consumed at t-1; reads retired pre-barrier
    }
    const short8* pA = (const short8*)(lA + pb * 16384);
    const short8* pB = (const short8*)(lB + pb * 8192);
    short8 af[2][4], bf[2][4];
#pragma unroll
    for (int i = 0; i < 4; i++) {
      const int r = 64 * wm + 16 * i + l15;
      af[0][i] = pA[r * 8 + (quad ^ (r & 7))];
      af[1][i] = pA[r * 8 + ((quad + 4) ^ (r & 7))];
      const int rb = 64 * wn + 16 * i + l15;
      bf[0][i] = pB[rb * 8 + (quad ^ (rb & 7))];
      bf[1][i] = pB[rb * 8 + ((quad + 4) ^ (rb & 7))];
    }
    __builtin_amdgcn_s_setprio(1);
#pragma unroll
    for (int i = 0; i < 4; i++)
#pragma unroll
      for (int j = 0; j < 4; j++)
        acc[i][j] = __builtin_amdgcn_mfma_f32_16x16x32_bf16(af[0][i], bf[0][j], acc[i][j], 0, 0, 0);
#pragma unroll
    for (int i = 0; i < 4; i++)
#pragma unroll
      for (int j = 0; j < 4; j++)
        acc[i][j] = __builtin_amdgcn_mfma_f32_16x16x32_bf16(af[1][i], bf[1][j], acc[i][j], 0, 0, 0);
    __builtin_amdgcn_s_setprio(0);
    if (t + 1 < NT) {
      if (t + 2 < NT) { asm volatile("s_waitcnt vmcnt(6)\n\ts_barrier" ::: "memory"); }
      else            { asm volatile("s_waitcnt vmcnt(0)\n\ts_barrier" ::: "memory"); }
    }
    pb = pb + 1; if (pb == 3) pb = 0;
  }

  float bs[4];
#pragma unroll
  for (int j = 0; j < 4; j++) bs[j] = bias[nt + 64 * wn + 16 * j + l15];
#pragma unroll
  for (int i = 0; i < 4; i++) {
#pragma unroll
    for (int r = 0; r < 4; r++) {
      const int gm = mt + 64 * wm + 16 * i + quad * 4 + r;
      float nrm = 0.f;
#pragma unroll
      for (int j = 0; j < 4; j++) {
        float v = acc[i][j][r] + bs[j];
        const int gn = nt + 64 * wn + 16 * j + l15;
        if (Cf) Cf[(size_t)gm * EE + gn] = v;
        if (Cb) Cb[(size_t)gm * EE + gn] = f2b(v);
        nrm += v * v;
      }
      if (scA) {
#pragma unroll
        for (int m = 1; m < 16; m <<= 1) nrm += __shfl_xor(nrm, m, 64);
        if (l15 == 0) atomicAdd(&scA[gm], sqrtf(nrm) * (1.f / 16.f));
      }
    }
  }
}

// ---------------- stage-1 topk: exact top-96 set per batch (order-free) ----------------
#define TKT 1024
#define EQCAP 256
__global__ __launch_bounds__(TKT) void topk1_k(const float* __restrict__ sc, int* __restrict__ cand) {
  const int b = blockIdx.x;
  __shared__ uint32_t s[SS];
  __shared__ int wsum[TKT / 64];
  __shared__ int cnt_sh;
  __shared__ int counter, eqcount;
  __shared__ int eqbuf[EQCAP];
  const int tid = threadIdx.x;
  const int lane = tid & 63, wv = tid >> 6;
  for (int i = tid; i < SS; i += TKT) s[i] = __float_as_uint(sc[b * SS + i]);
  if (tid == 0) { counter = 0; eqcount = 0; }
  __syncthreads();

  uint32_t lo = 0u, hi = 0x7f7fffffu;
  while (lo < hi) {
    uint32_t mid = lo + ((hi - lo + 1) >> 1);
    int c = 0;
    for (int i = tid; i < SS; i += TKT) c += (s[i] >= mid) ? 1 : 0;
#pragma unroll
    for (int m = 1; m < 64; m <<= 1) c += __shfl_xor(c, m, 64);
    if (lane == 0) wsum[wv] = c;
    __syncthreads();
    if (tid == 0) {
      int t = 0;
#pragma unroll
      for (int w = 0; w < TKT / 64; w++) t += wsum[w];
      cnt_sh = t;
    }
    __syncthreads();
    if (cnt_sh >= CANDN) lo = mid; else hi = mid - 1;
    __syncthreads();
  }
  const uint32_t T = lo;  // count(u>T) < CANDN <= count(u>=T)

  for (int i = tid; i < SS; i += TKT) {
    uint32_t u = s[i];
    if (u > T) {
      int p = atomicAdd(&counter, 1);
      cand[b * CANDN + p] = i;
    } else if (u == T) {
      int p = atomicAdd(&eqcount, 1);
      if (p < EQCAP) eqbuf[p] = i;
    }
  }
  __syncthreads();
  const int above = counter;
  const int rem = CANDN - above;
  int ec = eqcount; if (ec > EQCAP) ec = EQCAP;
  __syncthreads();
  for (int i = tid; i < ec; i += TKT) {
    int me = eqbuf[i];
    int rank = 0;
    for (int j = 0; j < ec; j++) rank += (eqbuf[j] < me) ? 1 : 0;
    if (rank < rem) {
      int p = atomicAdd(&counter, 1);
      cand[b * CANDN + p] = me;
    }
  }
}

// ---------------- stage-2: exact fp64 k for candidates ----------------
__global__ __launch_bounds__(256) void rescore_k(const float* __restrict__ key, const float* __restrict__ Wk,
                                                 const int* __restrict__ cand, double* __restrict__ kpart) {
  const int kc = blockIdx.x, h = blockIdx.y, b = blockIdx.z;
  const int d = threadIdx.x & 63, cg = threadIdx.x >> 6;
  __shared__ float wk[64 * 257];   // padded: 64 rows stride 257
  __shared__ float xs[24 * 256];
  for (int i = threadIdx.x; i < 64 * 256; i += 256)
    wk[(i >> 8) * 257 + (i & 255)] = Wk[(size_t)(h * 64 + (i >> 8)) * EE + kc * 256 + (i & 255)];
  for (int c0 = 0; c0 < CANDN; c0 += 24) {
    __syncthreads();
    for (int i = threadIdx.x; i < 24 * 256; i += 256) {
      int c = c0 + (i >> 8);
      xs[i] = key[((size_t)b * SS + cand[b * CANDN + c]) * EE + kc * 256 + (i & 255)];
    }
    __syncthreads();
    double acc[6] = {0, 0, 0, 0, 0, 0};
    for (int kk = 0; kk < 256; kk++) {
      double wv_ = (double)wk[d * 257 + kk];
#pragma unroll
      for (int j = 0; j < 6; j++)
        acc[j] += wv_ * (double)xs[(cg * 6 + j) * 256 + kk];
    }
#pragma unroll
    for (int j = 0; j < 6; j++) {
      int c = c0 + cg * 6 + j;
      kpart[(((size_t)kc * BB + b) * CANDN + c) * 1024 + h * 64 + d] = acc[j];
    }
  }
}

// exact fp64 candidate scores
__global__ __launch_bounds__(64) void score2_k(const double* __restrict__ kpart, const float* __restrict__ bk,
                                               double* __restrict__ sc2) {
  const int c = blockIdx.x, b = blockIdx.y;
  const int lane = threadIdx.x;
  double tot = 0.0;
  for (int h = 0; h < HH; h++) {
    double v = (double)bk[h * 64 + lane];
#pragma unroll
    for (int kc = 0; kc < 4; kc++)
      v += kpart[(((size_t)kc * BB + b) * CANDN + c) * 1024 + h * 64 + lane];
    double s = v * v;
#pragma unroll
    for (int m = 1; m < 64; m <<= 1) s += __shfl_xor(s, m, 64);
    tot += sqrt(s);
  }
  if (lane == 0) sc2[b * CANDN + c] = tot * (1.0 / 16.0);
}

// exact rank among candidates -> final idx in descending order (tie: lower index first)
__global__ __launch_bounds__(128) void topk2_k(const double* __restrict__ sc2, const int* __restrict__ cand,
                                               int* __restrict__ idxf) {
  const int b = blockIdx.x, t = threadIdx.x;
  if (t >= CANDN) return;
  double my = sc2[b * CANDN + t];
  int mi = cand[b * CANDN + t];
  int rank = 0;
  for (int j = 0; j < CANDN; j++) {
    double sj = sc2[b * CANDN + j];
    int ij = cand[b * CANDN + j];
    if (sj > my || (sj == my && ij < mi)) rank++;
  }
  if (rank < LL) idxf[b * LL + rank] = mi;
}

// gather value rows for the selected indices (fp32 -> bf16)
__global__ __launch_bounds__(256) void gatherx_k(const float* __restrict__ value, const int* __restrict__ idxf,
                                                 u16* __restrict__ xg) {
  const int r = blockIdx.x;  // b*64 + l
  const int b = r >> 6;
  const float* src = value + ((size_t)b * SS + idxf[r]) * EE;
  for (int i = threadIdx.x; i < EE; i += 256) xg[(size_t)r * EE + i] = f2b(src[i]);
}

// build k_sp[(b,h),l,d] (bf16) and v_spT[(b,h),d,l] (bf16)
__global__ __launch_bounds__(64) void gathersp_k(const u16* __restrict__ kb, const float* __restrict__ vg,
                                                 const int* __restrict__ idxf,
                                                 u16* __restrict__ ksp, u16* __restrict__ vspT) {
  const int g = blockIdx.x;  // (b*16+h)*64 + l
  const int l = g & 63, h = (g >> 6) & 15, b = g >> 10;
  const int d = threadIdx.x;
  ksp[(size_t)g * 64 + d] = kb[((size_t)b * SS + idxf[b * 64 + l]) * EE + h * 64 + d];
  vspT[((size_t)(b * 16 + h) * 64 + d) * 64 + l] = f2b(vg[((size_t)b * 64 + l) * EE + h * 64 + d]);
}

// ---------------- fused attention: QK^T -> softmax -> w out -> PV -> attn out ----------------
__global__ __launch_bounds__(256) void attn_k(const u16* __restrict__ qb, const u16* __restrict__ ksp,
                                              const u16* __restrict__ vspT,
                                              float* __restrict__ wout, u16* __restrict__ attnb) {
  __shared__ __align__(16) u16 qt[4096];
  __shared__ __align__(16) u16 kt[4096];
  __shared__ __align__(16) u16 vt[4096];
  __shared__ __align__(16) u16 wt[4096];
  const int tid = threadIdx.x;
  const int wv = tid >> 6, lane = tid & 63, quad = lane >> 4, l15 = lane & 15;
  const int s0 = blockIdx.x * 64;
  const int bh = blockIdx.y, b = bh >> 4, h = bh & 15;

  {
    const int bi0 = tid, bi1 = 256 + tid;
    const int r0 = bi0 >> 3, c0 = (bi0 & 7) ^ (r0 & 7);
    const int r1 = bi1 >> 3, c1 = (bi1 & 7) ^ (r1 & 7);
    const u16* qg = qb + ((size_t)b * SS + s0) * EE + h * 64;
    async16(qg + (size_t)r0 * EE + c0 * 8, qt + bi0 * 8);
    async16(qg + (size_t)r1 * EE + c1 * 8, qt + bi1 * 8);
    const u16* kg = ksp + (size_t)bh * 4096;
    async16(kg + r0 * 64 + c0 * 8, kt + bi0 * 8);
    async16(kg + r1 * 64 + c1 * 8, kt + bi1 * 8);
    const u16* vgp = vspT + (size_t)bh * 4096;
    async16(vgp + r0 * 64 + c0 * 8, vt + bi0 * 8);
    async16(vgp + r1 * 64 + c1 * 8, vt + bi1 * 8);
  }
  __syncthreads();

  f32x4 acc[4];
#pragma unroll
  for (int j = 0; j < 4; j++) acc[j] = (f32x4){0.f, 0.f, 0.f, 0.f};
  const int ar = 16 * wv + l15;
#pragma unroll
  for (int ks = 0; ks < 2; ks++) {
    const int cg = quad + ks * 4;
    short8 af = ((const short8*)qt)[ar * 8 + (cg ^ (ar & 7))];
#pragma unroll
    for (int j = 0; j < 4; j++) {
      int br = 16 * j + l15;
      short8 bf = ((const short8*)kt)[br * 8 + (cg ^ (br & 7))];
      acc[j] = __builtin_amdgcn_mfma_f32_16x16x32_bf16(af, bf, acc[j], 0, 0, 0);
    }
  }
#pragma unroll
  for (int j = 0; j < 4; j++) acc[j] *= 0.125f;  // 1/sqrt(D)

  float inv[4];
#pragma unroll
  for (int r = 0; r < 4; r++) {
    float m = fmaxf(fmaxf(acc[0][r], acc[1][r]), fmaxf(acc[2][r], acc[3][r]));
#pragma unroll
    for (int msk = 1; msk < 16; msk <<= 1) m = fmaxf(m, __shfl_xor(m, msk, 64));
    float e0 = __expf(acc[0][r] - m);
    float e1 = __expf(acc[1][r] - m);
    float e2 = __expf(acc[2][r] - m);
    float e3 = __expf(acc[3][r] - m);
    acc[0][r] = e0; acc[1][r] = e1; acc[2][r] = e2; acc[3][r] = e3;
    float s = e0 + e1 + e2 + e3;
#pragma unroll
    for (int msk = 1; msk < 16; msk <<= 1) s += __shfl_xor(s, msk, 64);
    inv[r] = 1.f / s;
  }

  const size_t wbase = ((size_t)bh * SS + s0 + 16 * wv) * 64;
#pragma unroll
  for (int j = 0; j < 4; j++) {
#pragma unroll
    for (int r = 0; r < 4; r++) {
      float val = acc[j][r] * inv[r];
      int rowl = quad * 4 + r;
      int l = 16 * j + l15;
      wout[wbase + (size_t)rowl * 64 + l] = val;
      int wr = 16 * wv + rowl;
      wt[wr * 64 + ((l >> 3) ^ (wr & 7)) * 8 + (l & 7)] = f2b(val);
    }
  }
  __syncthreads();

  f32x4 acc2[4];
#pragma unroll
  for (int j = 0; j < 4; j++) acc2[j] = (f32x4){0.f, 0.f, 0.f, 0.f};
#pragma unroll
  for (int ks = 0; ks < 2; ks++) {
    const int cg = quad + ks * 4;
    short8 af = ((const short8*)wt)[ar * 8 + (cg ^ (ar & 7))];
#pragma unroll
    for (int j = 0; j < 4; j++) {
      int br = 16 * j + l15;
      short8 bf = ((const short8*)vt)[br * 8 + (cg ^ (br & 7))];
      acc2[j] = __builtin_amdgcn_mfma_f32_16x16x32_bf16(af, bf, acc2[j], 0, 0, 0);
    }
  }
#pragma unroll
  for (int j = 0; j < 4; j++)
#pragma unroll
    for (int r = 0; r < 4; r++)
      attnb[((size_t)b * SS + s0 + 16 * wv + quad * 4 + r) * EE + h * 64 + 16 * j + l15] = f2b(acc2[j][r]);
}

extern "C" void kernel_launch(void* const* d_in, const int* in_sizes, int n_in,
                              void* d_out, int out_size, void* d_ws, size_t ws_size,
                              hipStream_t stream) {
  (void)in_sizes; (void)n_in; (void)out_size; (void)ws_size;
  const float* query = (const float*)d_in[0];
  const float* key   = (const float*)d_in[1];
  const float* value = (const float*)d_in[2];
  const float* Wq = (const float*)d_in[3];
  const float* bq = (const float*)d_in[4];
  const float* Wk = (const float*)d_in[5];
  const float* bk = (const float*)d_in[6];
  const float* Wv = (const float*)d_in[7];
  const float* bv = (const float*)d_in[8];
  const float* Wo = (const float*)d_in[9];
  const float* bo = (const float*)d_in[10];
  float* out = (float*)d_out;
  float* wout = out + (size_t)BB * SS * EE;

  char* p = (char*)d_ws;
  auto alloc = [&](size_t n) { char* r = p; p += (n + 255) & ~(size_t)255; return r; };
  u16* qbf = (u16*)alloc((size_t)BB * SS * EE * 2);   // query bf16; reused later as attn output
  u16* kbf = (u16*)alloc((size_t)BB * SS * EE * 2);
  u16* wqb = (u16*)alloc((size_t)EE * EE * 2);
  u16* wkb = (u16*)alloc((size_t)EE * EE * 2);
  u16* wvb = (u16*)alloc((size_t)EE * EE * 2);
  u16* wob = (u16*)alloc((size_t)EE * EE * 2);
  u16* qb  = (u16*)alloc((size_t)BB * SS * EE * 2);
  u16* kb  = (u16*)alloc((size_t)BB * SS * EE * 2);
  float*  sc    = (float*)alloc((size_t)BB * SS * 4);
  int*    cand  = (int*)alloc(BB * CANDN * 4);
  double* kpart = (double*)alloc((size_t)4 * BB * CANDN * 1024 * 8);
  double* sc2   = (double*)alloc(BB * CANDN * 8);
  int*    idxf  = (int*)alloc(BB * LL * 4);
  u16*    xg    = (u16*)alloc((size_t)BB * LL * EE * 2);
  float*  vg    = (float*)alloc((size_t)BB * LL * EE * 4);
  u16*    ksp   = (u16*)alloc((size_t)BB * HH * LL * DD * 2);
  u16*    vspT  = (u16*)alloc((size_t)BB * HH * DD * LL * 2);
  u16*    attnb = qbf;  // reuse: query_bf16 dead after Q GEMM

  const int M = BB * SS;
  const size_t gemm_lds = 147456;  // 3*(256*64 + 128*64) u16

  cvt_bf16_k<<<(M * EE / 4 + 255) / 256, 256, 0, stream>>>(query, qbf, M * EE / 4);
  cvt_bf16_k<<<(M * EE / 4 + 255) / 256, 256, 0, stream>>>(key, kbf, M * EE / 4);
  cvt_bf16_k<<<(EE * EE / 4 + 255) / 256, 256, 0, stream>>>(Wq, wqb, EE * EE / 4);
  cvt_bf16_k<<<(EE * EE / 4 + 255) / 256, 256, 0, stream>>>(Wk, wkb, EE * EE / 4);
  cvt_bf16_k<<<(EE * EE / 4 + 255) / 256, 256, 0, stream>>>(Wv, wvb, EE * EE / 4);
  cvt_bf16_k<<<(EE * EE / 4 + 255) / 256, 256, 0, stream>>>(Wo, wob, EE * EE / 4);
  hipMemsetAsync(sc, 0, (size_t)M * 4, stream);

  dim3 gg(EE / 128, M / 256);
  gemm256<<<gg, 512, gemm_lds, stream>>>(qbf, wqb, bq, nullptr, qb, nullptr, EE);  // Q projection
  gemm256<<<gg, 512, gemm_lds, stream>>>(kbf, wkb, bk, nullptr, kb, sc, EE);       // K proj + fused scores

  topk1_k<<<BB, TKT, 0, stream>>>(sc, cand);
  rescore_k<<<dim3(4, HH, BB), 256, 0, stream>>>(key, Wk, cand, kpart);
  score2_k<<<dim3(CANDN, BB), 64, 0, stream>>>(kpart, bk, sc2);
  topk2_k<<<BB, 128, 0, stream>>>(sc2, cand, idxf);

  gatherx_k<<<BB * LL, 256, 0, stream>>>(value, idxf, xg);
  gemm256<<<dim3(EE / 128, BB * LL / 256), 512, gemm_lds, stream>>>(xg, wvb, bv, vg, nullptr, nullptr, EE);  // V
  gathersp_k<<<BB * HH * LL, 64, 0, stream>>>(kb, vg, idxf, ksp, vspT);

  attn_k<<<dim3(SS / 64, BB * HH), 256, 0, stream>>>(qb, ksp, vspT, wout, attnb);

  gemm256<<<gg, 512, gemm_lds, stream>>>(attnb, wob, bo, out, nullptr, nullptr, EE); // output projection
}